// Round 11
// baseline (327.611 us; speedup 1.0000x reference)
//
#include <hip/hip_runtime.h>

// 2-layer GCN (GraphConv, norm='both') for N=50000, E=1600000, 128->128->40.
// Graph build: chunked counting sort, no global atomics.
// gemm1: MFMA bf16, writes h1 TILE-MAJOR [4][n][32f] (64B rows).
// Gathers: XCD-pinned feature tiles (tile t on XCDs 2t/2t+1, 3.2MB < 4MB L2),
// 1 node/wave, lane(g=e-slot,f=uint4-slot): 1KB/instr = 16 edges, unroll 2.
// Layer 2 commuted: y=ns*relu(L1) aggregated, then z'@W2+b2 -> d_out.

#define CHUNK 16384
#define CHUNK_SHIFT 14
#define NSLICES 64

typedef int iv4 __attribute__((ext_vector_type(4)));
typedef short short8 __attribute__((ext_vector_type(8)));
typedef float f32x4 __attribute__((ext_vector_type(4)));

__device__ __forceinline__ unsigned f2bf_bits(float f) {
    unsigned u = __float_as_uint(f);
    return (u + 0x7FFFu + ((u >> 16) & 1u)) >> 16;   // RNE
}
__device__ __forceinline__ unsigned pack_bf2(float a, float b) {
    return f2bf_bits(a) | (f2bf_bits(b) << 16);
}
__device__ __forceinline__ float bflo(unsigned v) { return __uint_as_float(v << 16); }
__device__ __forceinline__ float bfhi(unsigned v) { return __uint_as_float(v & 0xFFFF0000u); }

// ---------------- graph build ----------------

__global__ __launch_bounds__(256) void count_kernel(const int* __restrict__ src, const int* __restrict__ dst,
                                                    unsigned int* __restrict__ part, int E, int per) {
    __shared__ unsigned int h[CHUNK];
    int c = blockIdx.y, s = blockIdx.x, t = threadIdx.x;
    #pragma unroll
    for (int i = 0; i < CHUNK / 256; ++i) h[i * 256 + t] = 0;
    __syncthreads();
    int base = c << CHUNK_SHIFT;
    int beg = s * per;
    int end = min(E, beg + per);
    int nv = (end - beg) >> 2;
    const iv4* d4 = (const iv4*)(dst + beg);
    const iv4* s4 = (const iv4*)(src + beg);
    for (int i = t; i < nv; i += 256) {
        iv4 dv = __builtin_nontemporal_load(d4 + i);
        iv4 sv = __builtin_nontemporal_load(s4 + i);
        int x;
        x = dv.x - base; if ((unsigned)x < CHUNK) atomicAdd(&h[x], 1u);
        x = dv.y - base; if ((unsigned)x < CHUNK) atomicAdd(&h[x], 1u);
        x = dv.z - base; if ((unsigned)x < CHUNK) atomicAdd(&h[x], 1u);
        x = dv.w - base; if ((unsigned)x < CHUNK) atomicAdd(&h[x], 1u);
        x = sv.x - base; if ((unsigned)x < CHUNK) atomicAdd(&h[x], 0x10000u);
        x = sv.y - base; if ((unsigned)x < CHUNK) atomicAdd(&h[x], 0x10000u);
        x = sv.z - base; if ((unsigned)x < CHUNK) atomicAdd(&h[x], 0x10000u);
        x = sv.w - base; if ((unsigned)x < CHUNK) atomicAdd(&h[x], 0x10000u);
    }
    for (int e = beg + (nv << 2) + t; e < end; e += 256) {
        int x = dst[e] - base; if ((unsigned)x < CHUNK) atomicAdd(&h[x], 1u);
        x = src[e] - base;     if ((unsigned)x < CHUNK) atomicAdd(&h[x], 0x10000u);
    }
    __syncthreads();
    unsigned int* out = part + (((size_t)(c * NSLICES + s)) << CHUNK_SHIFT);
    #pragma unroll
    for (int i = 0; i < CHUNK / 256; ++i) __builtin_nontemporal_store(h[i * 256 + t], out + i * 256 + t);
}

__global__ __launch_bounds__(256) void reduce_kernel(const unsigned int* __restrict__ part,
                                                     float* __restrict__ norm_src, float* __restrict__ norm_dst,
                                                     int* __restrict__ deg_dst_i, int N) {
    int d = blockIdx.x * 256 + threadIdx.x;
    if (d >= N) return;
    int c = d >> CHUNK_SHIFT, idx = d & (CHUNK - 1);
    const unsigned int* p = part + (((size_t)c * NSLICES) << CHUNK_SHIFT) + idx;
    unsigned int dsum = 0, ssum = 0;
    #pragma unroll
    for (int s = 0; s < NSLICES; ++s) {
        unsigned int v = __builtin_nontemporal_load(p + ((size_t)s << CHUNK_SHIFT));
        dsum += v & 0xFFFFu;
        ssum += v >> 16;
    }
    deg_dst_i[d] = (int)dsum;
    norm_src[d] = rsqrtf(fmaxf((float)ssum, 1.0f));
    norm_dst[d] = rsqrtf(fmaxf((float)dsum, 1.0f));
}

__global__ __launch_bounds__(256) void scanA_kernel(const int* __restrict__ deg, int* __restrict__ bsum, int N) {
    __shared__ int wsum[4];
    int b = blockIdx.x, t = threadIdx.x, lane = t & 63, wid = t >> 6;
    int i0 = b * 1024 + t * 4;
    int s = 0;
    if (i0 + 3 < N) {
        int4 v = *(const int4*)(deg + i0);
        s = v.x + v.y + v.z + v.w;
    } else {
        for (int k = 0; k < 4; ++k) { int i = i0 + k; if (i < N) s += deg[i]; }
    }
    #pragma unroll
    for (int off = 32; off; off >>= 1) s += __shfl_down(s, off, 64);
    if (lane == 0) wsum[wid] = s;
    __syncthreads();
    if (t == 0) bsum[b] = wsum[0] + wsum[1] + wsum[2] + wsum[3];
}

__global__ __launch_bounds__(64) void scanB_kernel(int* __restrict__ bsum, int NB,
                                                   int* __restrict__ row_ptr, int N) {
    int t = threadIdx.x;
    int v = (t < NB) ? bsum[t] : 0;
    int x = v;
    #pragma unroll
    for (int off = 1; off < 64; off <<= 1) {
        int y = __shfl_up(x, off, 64);
        if (t >= off) x += y;
    }
    if (t < NB) bsum[t] = x - v;
    if (t == 63) row_ptr[N] = x;
}

__global__ __launch_bounds__(256) void scanC_kernel(const int* __restrict__ deg, const int* __restrict__ bsum,
                                                    int* __restrict__ row_ptr, int N) {
    __shared__ int wsum[4];
    int b = blockIdx.x, t = threadIdx.x, lane = t & 63, wid = t >> 6;
    int i0 = b * 1024 + t * 4;
    int4 v = make_int4(0, 0, 0, 0);
    if (i0 + 3 < N) v = *(const int4*)(deg + i0);
    else {
        v.x = (i0 < N) ? deg[i0] : 0;
        v.y = (i0 + 1 < N) ? deg[i0 + 1] : 0;
        v.z = (i0 + 2 < N) ? deg[i0 + 2] : 0;
        v.w = (i0 + 3 < N) ? deg[i0 + 3] : 0;
    }
    int tsum = v.x + v.y + v.z + v.w;
    int x = tsum;
    #pragma unroll
    for (int off = 1; off < 64; off <<= 1) {
        int y = __shfl_up(x, off, 64);
        if (lane >= off) x += y;
    }
    if (lane == 63) wsum[wid] = x;
    __syncthreads();
    int woff = 0;
    for (int k = 0; k < wid; ++k) woff += wsum[k];
    int base = bsum[b] + woff + (x - tsum);
    int e0 = base, e1 = e0 + v.x, e2 = e1 + v.y, e3 = e2 + v.z;
    if (i0 + 3 < N) *(int4*)(row_ptr + i0) = make_int4(e0, e1, e2, e3);
    else {
        if (i0 < N) row_ptr[i0] = e0;
        if (i0 + 1 < N) row_ptr[i0 + 1] = e1;
        if (i0 + 2 < N) row_ptr[i0 + 2] = e2;
        if (i0 + 3 < N) row_ptr[i0 + 3] = e3;
    }
}

__global__ __launch_bounds__(256) void offsets_kernel(unsigned int* __restrict__ part,
                                                      const int* __restrict__ row_ptr, int N) {
    int d = blockIdx.x * 256 + threadIdx.x;
    if (d >= N) return;
    int c = d >> CHUNK_SHIFT, idx = d & (CHUNK - 1);
    unsigned int* p = part + (((size_t)c * NSLICES) << CHUNK_SHIFT) + idx;
    unsigned int running = (unsigned int)row_ptr[d];
    #pragma unroll
    for (int s = 0; s < NSLICES; ++s) {
        unsigned int v = __builtin_nontemporal_load(p + ((size_t)s << CHUNK_SHIFT));
        __builtin_nontemporal_store(running, p + ((size_t)s << CHUNK_SHIFT));
        running += v & 0xFFFFu;
    }
}

__global__ __launch_bounds__(256) void scatter_kernel(const int* __restrict__ src, const int* __restrict__ dst,
                                                      const unsigned int* __restrict__ cum,
                                                      int* __restrict__ col, int E, int per) {
    __shared__ int cur[CHUNK];
    int c = blockIdx.y, s = blockIdx.x, t = threadIdx.x;
    const unsigned int* cc = cum + (((size_t)(c * NSLICES + s)) << CHUNK_SHIFT);
    #pragma unroll
    for (int i = 0; i < CHUNK / 256; ++i) cur[i * 256 + t] = (int)__builtin_nontemporal_load(cc + i * 256 + t);
    __syncthreads();
    int base = c << CHUNK_SHIFT;
    int beg = s * per;
    int end = min(E, beg + per);
    int nv = (end - beg) >> 2;
    const iv4* d4 = (const iv4*)(dst + beg);
    const iv4* s4 = (const iv4*)(src + beg);
    for (int i = t; i < nv; i += 256) {
        iv4 dv = __builtin_nontemporal_load(d4 + i);
        iv4 sv = __builtin_nontemporal_load(s4 + i);
        int x;
        x = dv.x - base; if ((unsigned)x < CHUNK) col[atomicAdd(&cur[x], 1)] = sv.x;
        x = dv.y - base; if ((unsigned)x < CHUNK) col[atomicAdd(&cur[x], 1)] = sv.y;
        x = dv.z - base; if ((unsigned)x < CHUNK) col[atomicAdd(&cur[x], 1)] = sv.z;
        x = dv.w - base; if ((unsigned)x < CHUNK) col[atomicAdd(&cur[x], 1)] = sv.w;
    }
    for (int e = beg + (nv << 2) + t; e < end; e += 256) {
        int x = dst[e] - base;
        if ((unsigned)x < CHUNK) col[atomicAdd(&cur[x], 1)] = src[e];
    }
}

// ---------------- dense layers ----------------

// wt[c][k] = bf16(W1[k][c]), 128x128. Grid 8 x 256 threads.
__global__ __launch_bounds__(256) void wprep_kernel(const float* __restrict__ W, unsigned short* __restrict__ wt) {
    int tid = blockIdx.x * 256 + threadIdx.x;   // 0..2047
    int c = tid & 127, kg = tid >> 7;           // kg 0..15
    unsigned p[4];
    #pragma unroll
    for (int j = 0; j < 4; ++j) {
        float v0 = W[(kg * 8 + 2 * j) * 128 + c];
        float v1 = W[(kg * 8 + 2 * j + 1) * 128 + c];
        p[j] = pack_bf2(v0, v1);
    }
    *(uint4*)(wt + (size_t)c * 128 + kg * 8) = make_uint4(p[0], p[1], p[2], p[3]);
}

// h1t[tile][n][32f] = bf16( (ns*x)bf16 @ W1 ) via mfma_f32_16x16x32_bf16.
__global__ __launch_bounds__(256) void gemm1_kernel(const float* __restrict__ x, const float* __restrict__ norm,
                                                    const unsigned short* __restrict__ wt,
                                                    unsigned short* __restrict__ h1u, int N, int NPAD) {
    __shared__ uint4 xs4[1024];                 // 64 rows x 256B (bf16, XOR-swizzled)
    char* xsb = (char*)xs4;
    int t = threadIdx.x;
    int rb = blockIdx.x * 64;
    #pragma unroll
    for (int i = 0; i < 8; ++i) {
        int idx = i * 256 + t;
        int row = idx >> 5, k4 = (idx & 31) << 2;
        int gr = rb + row;
        float4 v = make_float4(0.f, 0.f, 0.f, 0.f);
        if (gr < N) {
            v = *(const float4*)(x + (size_t)gr * 128 + k4);
            float nm = norm[gr];
            v.x *= nm; v.y *= nm; v.z *= nm; v.w *= nm;
        }
        int boff = row * 256 + ((k4 * 2) ^ ((row & 7) << 4));
        *(uint2*)(xsb + boff) = make_uint2(pack_bf2(v.x, v.y), pack_bf2(v.z, v.w));
    }
    __syncthreads();
    int w = t >> 6, lane = t & 63;
    int lrow = lane & 15, g = lane >> 4;
    int sw = (lrow & 7) << 4;
    int rloc = (w << 4) + lrow;
    short8 a[4];
    #pragma unroll
    for (int kt = 0; kt < 4; ++kt)
        a[kt] = *(const short8*)(xsb + rloc * 256 + ((kt * 64 + g * 16) ^ sw));
    f32x4 acc[8];
    #pragma unroll
    for (int ct = 0; ct < 8; ++ct) acc[ct] = (f32x4){0.f, 0.f, 0.f, 0.f};
    #pragma unroll
    for (int ct = 0; ct < 8; ++ct) {
        const unsigned short* wb = wt + (size_t)(ct * 16 + lrow) * 128 + g * 8;
        short8 b0 = *(const short8*)(wb);
        short8 b1 = *(const short8*)(wb + 32);
        short8 b2 = *(const short8*)(wb + 64);
        short8 b3 = *(const short8*)(wb + 96);
        acc[ct] = __builtin_amdgcn_mfma_f32_16x16x32_bf16(a[0], b0, acc[ct], 0, 0, 0);
        acc[ct] = __builtin_amdgcn_mfma_f32_16x16x32_bf16(a[1], b1, acc[ct], 0, 0, 0);
        acc[ct] = __builtin_amdgcn_mfma_f32_16x16x32_bf16(a[2], b2, acc[ct], 0, 0, 0);
        acc[ct] = __builtin_amdgcn_mfma_f32_16x16x32_bf16(a[3], b3, acc[ct], 0, 0, 0);
    }
    int rbase = rb + (w << 4) + g * 4;
    #pragma unroll
    for (int reg = 0; reg < 4; ++reg) {
        int rowg = rbase + reg;
        if (rowg < N) {
            #pragma unroll
            for (int ct = 0; ct < 8; ++ct) {
                int c = ct * 16 + lrow;
                h1u[(size_t)(c >> 5) * NPAD * 32 + (size_t)rowg * 32 + (c & 31)] =
                    (unsigned short)f2bf_bits(acc[ct][reg]);
            }
        }
    }
}

// ---------------- tiled gathers (tile t pinned to XCDs 2t/2t+1) ----------------

#define ACC8(v)  { a0 += bflo(v.x); a1 += bfhi(v.x); a2 += bflo(v.y); a3 += bfhi(v.y); \
                   a4 += bflo(v.z); a5 += bfhi(v.z); a6 += bflo(v.w); a7 += bfhi(v.w); }
#define RED16()  { a0 += __shfl_xor(a0, 4, 64); a0 += __shfl_xor(a0, 8, 64); a0 += __shfl_xor(a0, 16, 64); a0 += __shfl_xor(a0, 32, 64); \
                   a1 += __shfl_xor(a1, 4, 64); a1 += __shfl_xor(a1, 8, 64); a1 += __shfl_xor(a1, 16, 64); a1 += __shfl_xor(a1, 32, 64); \
                   a2 += __shfl_xor(a2, 4, 64); a2 += __shfl_xor(a2, 8, 64); a2 += __shfl_xor(a2, 16, 64); a2 += __shfl_xor(a2, 32, 64); \
                   a3 += __shfl_xor(a3, 4, 64); a3 += __shfl_xor(a3, 8, 64); a3 += __shfl_xor(a3, 16, 64); a3 += __shfl_xor(a3, 32, 64); \
                   a4 += __shfl_xor(a4, 4, 64); a4 += __shfl_xor(a4, 8, 64); a4 += __shfl_xor(a4, 16, 64); a4 += __shfl_xor(a4, 32, 64); \
                   a5 += __shfl_xor(a5, 4, 64); a5 += __shfl_xor(a5, 8, 64); a5 += __shfl_xor(a5, 16, 64); a5 += __shfl_xor(a5, 32, 64); \
                   a6 += __shfl_xor(a6, 4, 64); a6 += __shfl_xor(a6, 8, 64); a6 += __shfl_xor(a6, 16, 64); a6 += __shfl_xor(a6, 32, 64); \
                   a7 += __shfl_xor(a7, 4, 64); a7 += __shfl_xor(a7, 8, 64); a7 += __shfl_xor(a7, 16, 64); a7 += __shfl_xor(a7, 32, 64); }

// y[tile][n][32] = ns * relu( (sum h1t[tile][src][32]) * nd + b1[tile*32..] )
__global__ __launch_bounds__(256) void agg1_kernel(const int* __restrict__ row_ptr, const int* __restrict__ col,
                                                   const uint4* __restrict__ h1t, const float* __restrict__ norm_dst,
                                                   const float* __restrict__ norm_src, const float* __restrict__ b1,
                                                   uint4* __restrict__ yt, int N, int NPAD, int Bt) {
    int bid = blockIdx.x;
    int xcd = bid & 7, tile = xcd >> 1;
    int nblk = (bid >> 3) * 2 + (xcd & 1);
    if (nblk >= Bt) return;
    int t = threadIdx.x, wid = t >> 6, lane = t & 63;
    int g = lane >> 2, f = lane & 3;
    int n = nblk * 4 + wid;
    if (n >= N) return;
    int beg = row_ptr[n], deg = row_ptr[n + 1] - beg;
    const int* cp = col + beg;
    const uint4* hb = h1t + (size_t)tile * NPAD * 4 + f;
    float a0 = 0, a1 = 0, a2 = 0, a3 = 0, a4 = 0, a5 = 0, a6 = 0, a7 = 0;
    int e = 0;
    for (; e + 32 <= deg; e += 32) {
        int s0 = __builtin_nontemporal_load(cp + e + g);
        int s1 = __builtin_nontemporal_load(cp + e + 16 + g);
        uint4 v0 = hb[(size_t)s0 * 4];
        uint4 v1 = hb[(size_t)s1 * 4];
        ACC8(v0); ACC8(v1);
    }
    for (; e < deg; e += 16) {
        int idx = e + g;
        if (idx < deg) {
            uint4 v = hb[(size_t)__builtin_nontemporal_load(cp + idx) * 4];
            ACC8(v);
        }
    }
    RED16();
    if (g == 0) {
        float nd = norm_dst[n];
        float ns = norm_src[n];
        const float* bb = b1 + tile * 32 + f * 8;
        float4 bA = *(const float4*)(bb);
        float4 bB = *(const float4*)(bb + 4);
        float o0 = ns * fmaxf(a0 * nd + bA.x, 0.f);
        float o1 = ns * fmaxf(a1 * nd + bA.y, 0.f);
        float o2 = ns * fmaxf(a2 * nd + bA.z, 0.f);
        float o3 = ns * fmaxf(a3 * nd + bA.w, 0.f);
        float o4 = ns * fmaxf(a4 * nd + bB.x, 0.f);
        float o5 = ns * fmaxf(a5 * nd + bB.y, 0.f);
        float o6 = ns * fmaxf(a6 * nd + bB.z, 0.f);
        float o7 = ns * fmaxf(a7 * nd + bB.w, 0.f);
        uint4 p;
        p.x = pack_bf2(o0, o1); p.y = pack_bf2(o2, o3);
        p.z = pack_bf2(o4, o5); p.w = pack_bf2(o6, o7);
        yt[(size_t)tile * NPAD * 4 + (size_t)n * 4 + f] = p;
    }
}

// z'[tile][n][32] = nd * sum y[tile][src][32]
__global__ __launch_bounds__(256) void aggY_kernel(const int* __restrict__ row_ptr, const int* __restrict__ col,
                                                   const uint4* __restrict__ yt, const float* __restrict__ norm_dst,
                                                   uint4* __restrict__ zt, int N, int NPAD, int Bt) {
    int bid = blockIdx.x;
    int xcd = bid & 7, tile = xcd >> 1;
    int nblk = (bid >> 3) * 2 + (xcd & 1);
    if (nblk >= Bt) return;
    int t = threadIdx.x, wid = t >> 6, lane = t & 63;
    int g = lane >> 2, f = lane & 3;
    int n = nblk * 4 + wid;
    if (n >= N) return;
    int beg = row_ptr[n], deg = row_ptr[n + 1] - beg;
    const int* cp = col + beg;
    const uint4* hb = yt + (size_t)tile * NPAD * 4 + f;
    float a0 = 0, a1 = 0, a2 = 0, a3 = 0, a4 = 0, a5 = 0, a6 = 0, a7 = 0;
    int e = 0;
    for (; e + 32 <= deg; e += 32) {
        int s0 = __builtin_nontemporal_load(cp + e + g);
        int s1 = __builtin_nontemporal_load(cp + e + 16 + g);
        uint4 v0 = hb[(size_t)s0 * 4];
        uint4 v1 = hb[(size_t)s1 * 4];
        ACC8(v0); ACC8(v1);
    }
    for (; e < deg; e += 16) {
        int idx = e + g;
        if (idx < deg) {
            uint4 v = hb[(size_t)__builtin_nontemporal_load(cp + idx) * 4];
            ACC8(v);
        }
    }
    RED16();
    if (g == 0) {
        float nd = norm_dst[n];
        uint4 p;
        p.x = pack_bf2(a0 * nd, a1 * nd); p.y = pack_bf2(a2 * nd, a3 * nd);
        p.z = pack_bf2(a4 * nd, a5 * nd); p.w = pack_bf2(a6 * nd, a7 * nd);
        zt[(size_t)tile * NPAD * 4 + (size_t)n * 4 + f] = p;
    }
}

// out[n][j] = sum_k z'[n][k] * W2[k][j] + b2[j]  (z' tile-major, fp32 out)
__global__ __launch_bounds__(256) void gemmOut_kernel(const unsigned int* __restrict__ zp,
                                                      const float* __restrict__ W, const float* __restrict__ b2,
                                                      float* __restrict__ out, int N, int NPAD) {
    __shared__ float xs[128 * 64];
    __shared__ float ws2[128 * 40];
    int t = threadIdx.x;
    int rb = blockIdx.x * 64;
    #pragma unroll
    for (int i = 0; i < 5; ++i) {
        int idx = i * 256 + t;
        *(float4*)(ws2 + idx * 4) = *(const float4*)(W + idx * 4);
    }
    #pragma unroll
    for (int i = 0; i < 16; ++i) {
        int idx = i * 256 + t;               // 64 rows x 64 k-pairs
        int row = idx >> 6, kp = idx & 63;
        int gr = rb + row;
        unsigned v = 0;
        if (gr < N) v = zp[(size_t)(kp >> 4) * NPAD * 16 + (size_t)gr * 16 + (kp & 15)];
        int r = row ^ (((kp >> 1) & 7) << 2);
        xs[(2 * kp + 0) * 64 + r] = bflo(v);
        xs[(2 * kp + 1) * 64 + r] = bfhi(v);
    }
    __syncthreads();
    int jg = t & 7, rg = t >> 3;
    int j = jg * 5, r0 = rg << 1;
    float acc0[5] = {0, 0, 0, 0, 0};
    float acc1[5] = {0, 0, 0, 0, 0};
    #pragma unroll 4
    for (int k = 0; k < 128; ++k) {
        int sw = ((k >> 2) & 7) << 2;
        float2 xv = *(const float2*)&xs[k * 64 + (r0 ^ sw)];
        #pragma unroll
        for (int c = 0; c < 5; ++c) {
            float w = ws2[k * 40 + j + c];
            acc0[c] += xv.x * w;
            acc1[c] += xv.y * w;
        }
    }
    int gr0 = rb + r0;
    if (gr0 < N) {
        #pragma unroll
        for (int c = 0; c < 5; ++c) out[(size_t)gr0 * 40 + j + c] = acc0[c] + b2[j + c];
    }
    if (gr0 + 1 < N) {
        #pragma unroll
        for (int c = 0; c < 5; ++c) out[(size_t)(gr0 + 1) * 40 + j + c] = acc1[c] + b2[j + c];
    }
}

extern "C" void kernel_launch(void* const* d_in, const int* in_sizes, int n_in,
                              void* d_out, int out_size, void* d_ws, size_t ws_size,
                              hipStream_t stream) {
    const float* x  = (const float*)d_in[0];
    const int* src  = (const int*)d_in[1];
    const int* dst  = (const int*)d_in[2];
    const float* W1 = (const float*)d_in[3];
    const float* b1 = (const float*)d_in[4];
    const float* W2 = (const float*)d_in[5];
    const float* b2 = (const float*)d_in[6];
    float* out = (float*)d_out;

    int N = in_sizes[0] / 128;
    int E = in_sizes[1];
    int NPAD = (N + 63) & ~63;
    int NCHUNKS = (N + CHUNK - 1) >> CHUNK_SHIFT;
    int per = ((E + NSLICES - 1) / NSLICES + 3) & ~3;
    int NB = (N + 1023) / 1024;

    float* ws = (float*)d_ws;
    float* norm_src = ws;                                       // NPAD floats
    float* norm_dst = ws + NPAD;                                // NPAD floats
    int* deg_dst_i  = (int*)(ws + 2 * (size_t)NPAD);            // NPAD ints
    int* row_ptr    = (int*)(ws + 3 * (size_t)NPAD);            // N+1 ints
    int* bsum       = (int*)(ws + 4 * (size_t)NPAD);            // NB (<=64) ints
    unsigned short* wt1 = (unsigned short*)(ws + 4 * (size_t)NPAD + 64);   // 16384 bf16
    int* col        = (int*)(ws + 4 * (size_t)NPAD + 64 + 8192);           // E ints
    size_t h1_off   = ((size_t)4 * NPAD + 64 + 8192 + E + 15) & ~(size_t)15;
    unsigned short* h1u = (unsigned short*)(ws + h1_off);       // 4*NPAD*32 bf16 (12.8MB)
    uint4* h1q      = (uint4*)h1u;
    uint4* yq       = h1q + (size_t)NPAD * 16;                  // 4*NPAD*32 bf16 (slot 2)
    uint4* zq       = h1q;                                      // reuse h1 slot (dead after agg1)
    unsigned int* zp = (unsigned int*)zq;
    unsigned int* part = (unsigned int*)h1u;                    // 16.8MB, dead before gemm1

    dim3 cgrid(NSLICES, NCHUNKS);
    wprep_kernel<<<8, 256, 0, stream>>>(W1, wt1);
    count_kernel<<<cgrid, 256, 0, stream>>>(src, dst, part, E, per);
    reduce_kernel<<<(N + 255) / 256, 256, 0, stream>>>(part, norm_src, norm_dst, deg_dst_i, N);
    scanA_kernel<<<NB, 256, 0, stream>>>(deg_dst_i, bsum, N);
    scanB_kernel<<<1, 64, 0, stream>>>(bsum, NB, row_ptr, N);
    scanC_kernel<<<NB, 256, 0, stream>>>(deg_dst_i, bsum, row_ptr, N);
    offsets_kernel<<<(N + 255) / 256, 256, 0, stream>>>(part, row_ptr, N);
    scatter_kernel<<<cgrid, 256, 0, stream>>>(src, dst, part, col, E, per);
    gemm1_kernel<<<(N + 63) / 64, 256, 0, stream>>>(x, norm_src, wt1, h1u, N, NPAD);
    int Bt = (N + 3) / 4;
    int P = (Bt + 1) / 2;
    agg1_kernel<<<8 * P, 256, 0, stream>>>(row_ptr, col, h1q, norm_dst, norm_src, b1, yq, N, NPAD, Bt);
    aggY_kernel<<<8 * P, 256, 0, stream>>>(row_ptr, col, yq, norm_dst, zq, N, NPAD, Bt);
    gemmOut_kernel<<<(N + 63) / 64, 256, 0, stream>>>(zp, W2, b2, out, N, NPAD);
}

// Round 12
// 208.176 us; speedup vs baseline: 1.5737x; 1.5737x over previous
//
#include <hip/hip_runtime.h>

// 2-layer GCN (GraphConv, norm='both') for N=50000, E=1600000, 128->128->40.
// Graph build: chunked counting sort, no global atomics.
// gemm1: MFMA bf16 -> h1 [n][128] bf16. agg1: one node/wave uint4 gather.
// W2 commuted BEFORE 2nd aggregation: w = y@W2 (MFMA, padded to 64 bf16,
// 128B rows), aggZ gathers w (half the bytes of y) and writes d_out directly.

#define CHUNK 16384
#define CHUNK_SHIFT 14
#define NSLICES 64

typedef int iv4 __attribute__((ext_vector_type(4)));
typedef short short8 __attribute__((ext_vector_type(8)));
typedef float f32x4 __attribute__((ext_vector_type(4)));

__device__ __forceinline__ unsigned f2bf_bits(float f) {
    unsigned u = __float_as_uint(f);
    return (u + 0x7FFFu + ((u >> 16) & 1u)) >> 16;   // RNE
}
__device__ __forceinline__ unsigned pack_bf2(float a, float b) {
    return f2bf_bits(a) | (f2bf_bits(b) << 16);
}
__device__ __forceinline__ float bflo(unsigned v) { return __uint_as_float(v << 16); }
__device__ __forceinline__ float bfhi(unsigned v) { return __uint_as_float(v & 0xFFFF0000u); }

// ---------------- graph build ----------------

__global__ __launch_bounds__(256) void count_kernel(const int* __restrict__ src, const int* __restrict__ dst,
                                                    unsigned int* __restrict__ part, int E, int per) {
    __shared__ unsigned int h[CHUNK];
    int c = blockIdx.y, s = blockIdx.x, t = threadIdx.x;
    #pragma unroll
    for (int i = 0; i < CHUNK / 256; ++i) h[i * 256 + t] = 0;
    __syncthreads();
    int base = c << CHUNK_SHIFT;
    int beg = s * per;
    int end = min(E, beg + per);
    int nv = (end - beg) >> 2;
    const iv4* d4 = (const iv4*)(dst + beg);
    const iv4* s4 = (const iv4*)(src + beg);
    for (int i = t; i < nv; i += 256) {
        iv4 dv = __builtin_nontemporal_load(d4 + i);
        iv4 sv = __builtin_nontemporal_load(s4 + i);
        int x;
        x = dv.x - base; if ((unsigned)x < CHUNK) atomicAdd(&h[x], 1u);
        x = dv.y - base; if ((unsigned)x < CHUNK) atomicAdd(&h[x], 1u);
        x = dv.z - base; if ((unsigned)x < CHUNK) atomicAdd(&h[x], 1u);
        x = dv.w - base; if ((unsigned)x < CHUNK) atomicAdd(&h[x], 1u);
        x = sv.x - base; if ((unsigned)x < CHUNK) atomicAdd(&h[x], 0x10000u);
        x = sv.y - base; if ((unsigned)x < CHUNK) atomicAdd(&h[x], 0x10000u);
        x = sv.z - base; if ((unsigned)x < CHUNK) atomicAdd(&h[x], 0x10000u);
        x = sv.w - base; if ((unsigned)x < CHUNK) atomicAdd(&h[x], 0x10000u);
    }
    for (int e = beg + (nv << 2) + t; e < end; e += 256) {
        int x = dst[e] - base; if ((unsigned)x < CHUNK) atomicAdd(&h[x], 1u);
        x = src[e] - base;     if ((unsigned)x < CHUNK) atomicAdd(&h[x], 0x10000u);
    }
    __syncthreads();
    unsigned int* out = part + (((size_t)(c * NSLICES + s)) << CHUNK_SHIFT);
    #pragma unroll
    for (int i = 0; i < CHUNK / 256; ++i) __builtin_nontemporal_store(h[i * 256 + t], out + i * 256 + t);
}

__global__ __launch_bounds__(256) void reduce_kernel(const unsigned int* __restrict__ part,
                                                     float* __restrict__ norm_src, float* __restrict__ norm_dst,
                                                     int* __restrict__ deg_dst_i, int N) {
    int d = blockIdx.x * 256 + threadIdx.x;
    if (d >= N) return;
    int c = d >> CHUNK_SHIFT, idx = d & (CHUNK - 1);
    const unsigned int* p = part + (((size_t)c * NSLICES) << CHUNK_SHIFT) + idx;
    unsigned int dsum = 0, ssum = 0;
    #pragma unroll
    for (int s = 0; s < NSLICES; ++s) {
        unsigned int v = __builtin_nontemporal_load(p + ((size_t)s << CHUNK_SHIFT));
        dsum += v & 0xFFFFu;
        ssum += v >> 16;
    }
    deg_dst_i[d] = (int)dsum;
    norm_src[d] = rsqrtf(fmaxf((float)ssum, 1.0f));
    norm_dst[d] = rsqrtf(fmaxf((float)dsum, 1.0f));
}

__global__ __launch_bounds__(256) void scanA_kernel(const int* __restrict__ deg, int* __restrict__ bsum, int N) {
    __shared__ int wsum[4];
    int b = blockIdx.x, t = threadIdx.x, lane = t & 63, wid = t >> 6;
    int i0 = b * 1024 + t * 4;
    int s = 0;
    if (i0 + 3 < N) {
        int4 v = *(const int4*)(deg + i0);
        s = v.x + v.y + v.z + v.w;
    } else {
        for (int k = 0; k < 4; ++k) { int i = i0 + k; if (i < N) s += deg[i]; }
    }
    #pragma unroll
    for (int off = 32; off; off >>= 1) s += __shfl_down(s, off, 64);
    if (lane == 0) wsum[wid] = s;
    __syncthreads();
    if (t == 0) bsum[b] = wsum[0] + wsum[1] + wsum[2] + wsum[3];
}

__global__ __launch_bounds__(64) void scanB_kernel(int* __restrict__ bsum, int NB,
                                                   int* __restrict__ row_ptr, int N) {
    int t = threadIdx.x;
    int v = (t < NB) ? bsum[t] : 0;
    int x = v;
    #pragma unroll
    for (int off = 1; off < 64; off <<= 1) {
        int y = __shfl_up(x, off, 64);
        if (t >= off) x += y;
    }
    if (t < NB) bsum[t] = x - v;
    if (t == 63) row_ptr[N] = x;
}

__global__ __launch_bounds__(256) void scanC_kernel(const int* __restrict__ deg, const int* __restrict__ bsum,
                                                    int* __restrict__ row_ptr, int N) {
    __shared__ int wsum[4];
    int b = blockIdx.x, t = threadIdx.x, lane = t & 63, wid = t >> 6;
    int i0 = b * 1024 + t * 4;
    int4 v = make_int4(0, 0, 0, 0);
    if (i0 + 3 < N) v = *(const int4*)(deg + i0);
    else {
        v.x = (i0 < N) ? deg[i0] : 0;
        v.y = (i0 + 1 < N) ? deg[i0 + 1] : 0;
        v.z = (i0 + 2 < N) ? deg[i0 + 2] : 0;
        v.w = (i0 + 3 < N) ? deg[i0 + 3] : 0;
    }
    int tsum = v.x + v.y + v.z + v.w;
    int x = tsum;
    #pragma unroll
    for (int off = 1; off < 64; off <<= 1) {
        int y = __shfl_up(x, off, 64);
        if (lane >= off) x += y;
    }
    if (lane == 63) wsum[wid] = x;
    __syncthreads();
    int woff = 0;
    for (int k = 0; k < wid; ++k) woff += wsum[k];
    int base = bsum[b] + woff + (x - tsum);
    int e0 = base, e1 = e0 + v.x, e2 = e1 + v.y, e3 = e2 + v.z;
    if (i0 + 3 < N) *(int4*)(row_ptr + i0) = make_int4(e0, e1, e2, e3);
    else {
        if (i0 < N) row_ptr[i0] = e0;
        if (i0 + 1 < N) row_ptr[i0 + 1] = e1;
        if (i0 + 2 < N) row_ptr[i0 + 2] = e2;
        if (i0 + 3 < N) row_ptr[i0 + 3] = e3;
    }
}

__global__ __launch_bounds__(256) void offsets_kernel(unsigned int* __restrict__ part,
                                                      const int* __restrict__ row_ptr, int N) {
    int d = blockIdx.x * 256 + threadIdx.x;
    if (d >= N) return;
    int c = d >> CHUNK_SHIFT, idx = d & (CHUNK - 1);
    unsigned int* p = part + (((size_t)c * NSLICES) << CHUNK_SHIFT) + idx;
    unsigned int running = (unsigned int)row_ptr[d];
    #pragma unroll
    for (int s = 0; s < NSLICES; ++s) {
        unsigned int v = __builtin_nontemporal_load(p + ((size_t)s << CHUNK_SHIFT));
        __builtin_nontemporal_store(running, p + ((size_t)s << CHUNK_SHIFT));
        running += v & 0xFFFFu;
    }
}

__global__ __launch_bounds__(256) void scatter_kernel(const int* __restrict__ src, const int* __restrict__ dst,
                                                      const unsigned int* __restrict__ cum,
                                                      int* __restrict__ col, int E, int per) {
    __shared__ int cur[CHUNK];
    int c = blockIdx.y, s = blockIdx.x, t = threadIdx.x;
    const unsigned int* cc = cum + (((size_t)(c * NSLICES + s)) << CHUNK_SHIFT);
    #pragma unroll
    for (int i = 0; i < CHUNK / 256; ++i) cur[i * 256 + t] = (int)__builtin_nontemporal_load(cc + i * 256 + t);
    __syncthreads();
    int base = c << CHUNK_SHIFT;
    int beg = s * per;
    int end = min(E, beg + per);
    int nv = (end - beg) >> 2;
    const iv4* d4 = (const iv4*)(dst + beg);
    const iv4* s4 = (const iv4*)(src + beg);
    for (int i = t; i < nv; i += 256) {
        iv4 dv = __builtin_nontemporal_load(d4 + i);
        iv4 sv = __builtin_nontemporal_load(s4 + i);
        int x;
        x = dv.x - base; if ((unsigned)x < CHUNK) col[atomicAdd(&cur[x], 1)] = sv.x;
        x = dv.y - base; if ((unsigned)x < CHUNK) col[atomicAdd(&cur[x], 1)] = sv.y;
        x = dv.z - base; if ((unsigned)x < CHUNK) col[atomicAdd(&cur[x], 1)] = sv.z;
        x = dv.w - base; if ((unsigned)x < CHUNK) col[atomicAdd(&cur[x], 1)] = sv.w;
    }
    for (int e = beg + (nv << 2) + t; e < end; e += 256) {
        int x = dst[e] - base;
        if ((unsigned)x < CHUNK) col[atomicAdd(&cur[x], 1)] = src[e];
    }
}

// ---------------- dense layers ----------------

// wt[c][k] = bf16(W1[k][c]), 128x128. Grid 8 x 256 threads.
__global__ __launch_bounds__(256) void wprep_kernel(const float* __restrict__ W, unsigned short* __restrict__ wt) {
    int tid = blockIdx.x * 256 + threadIdx.x;   // 0..2047
    int c = tid & 127, kg = tid >> 7;           // kg 0..15
    unsigned p[4];
    #pragma unroll
    for (int j = 0; j < 4; ++j) {
        float v0 = W[(kg * 8 + 2 * j) * 128 + c];
        float v1 = W[(kg * 8 + 2 * j + 1) * 128 + c];
        p[j] = pack_bf2(v0, v1);
    }
    *(uint4*)(wt + (size_t)c * 128 + kg * 8) = make_uint4(p[0], p[1], p[2], p[3]);
}

// wt2[c][k] = bf16(W2[k][c]) for c<40, zeros for 40<=c<48. Grid 3 x 256.
__global__ __launch_bounds__(256) void wprep2_kernel(const float* __restrict__ W2, unsigned short* __restrict__ wt2) {
    int tid = blockIdx.x * 256 + threadIdx.x;   // 0..767
    int c = tid >> 4, kg = tid & 15;            // c 0..47, kg 0..15
    unsigned p[4];
    #pragma unroll
    for (int j = 0; j < 4; ++j) {
        float v0 = (c < 40) ? W2[(kg * 8 + 2 * j) * 40 + c] : 0.f;
        float v1 = (c < 40) ? W2[(kg * 8 + 2 * j + 1) * 40 + c] : 0.f;
        p[j] = pack_bf2(v0, v1);
    }
    *(uint4*)(wt2 + (size_t)c * 128 + kg * 8) = make_uint4(p[0], p[1], p[2], p[3]);
}

// h1[n][j] = bf16( (ns*x)bf16 @ W1 ) via mfma_f32_16x16x32_bf16, flat [n][128].
__global__ __launch_bounds__(256) void gemm1_kernel(const float* __restrict__ x, const float* __restrict__ norm,
                                                    const unsigned short* __restrict__ wt,
                                                    unsigned short* __restrict__ h1u, int N) {
    __shared__ uint4 xs4[1024];                 // 64 rows x 256B (bf16, XOR-swizzled)
    char* xsb = (char*)xs4;
    int t = threadIdx.x;
    int rb = blockIdx.x * 64;
    #pragma unroll
    for (int i = 0; i < 8; ++i) {
        int idx = i * 256 + t;
        int row = idx >> 5, k4 = (idx & 31) << 2;
        int gr = rb + row;
        float4 v = make_float4(0.f, 0.f, 0.f, 0.f);
        if (gr < N) {
            v = *(const float4*)(x + (size_t)gr * 128 + k4);
            float nm = norm[gr];
            v.x *= nm; v.y *= nm; v.z *= nm; v.w *= nm;
        }
        int boff = row * 256 + ((k4 * 2) ^ ((row & 7) << 4));
        *(uint2*)(xsb + boff) = make_uint2(pack_bf2(v.x, v.y), pack_bf2(v.z, v.w));
    }
    __syncthreads();
    int w = t >> 6, lane = t & 63;
    int lrow = lane & 15, g = lane >> 4;
    int sw = (lrow & 7) << 4;
    int rloc = (w << 4) + lrow;
    short8 a[4];
    #pragma unroll
    for (int kt = 0; kt < 4; ++kt)
        a[kt] = *(const short8*)(xsb + rloc * 256 + ((kt * 64 + g * 16) ^ sw));
    f32x4 acc[8];
    #pragma unroll
    for (int ct = 0; ct < 8; ++ct) acc[ct] = (f32x4){0.f, 0.f, 0.f, 0.f};
    #pragma unroll
    for (int ct = 0; ct < 8; ++ct) {
        const unsigned short* wb = wt + (size_t)(ct * 16 + lrow) * 128 + g * 8;
        short8 b0 = *(const short8*)(wb);
        short8 b1 = *(const short8*)(wb + 32);
        short8 b2 = *(const short8*)(wb + 64);
        short8 b3 = *(const short8*)(wb + 96);
        acc[ct] = __builtin_amdgcn_mfma_f32_16x16x32_bf16(a[0], b0, acc[ct], 0, 0, 0);
        acc[ct] = __builtin_amdgcn_mfma_f32_16x16x32_bf16(a[1], b1, acc[ct], 0, 0, 0);
        acc[ct] = __builtin_amdgcn_mfma_f32_16x16x32_bf16(a[2], b2, acc[ct], 0, 0, 0);
        acc[ct] = __builtin_amdgcn_mfma_f32_16x16x32_bf16(a[3], b3, acc[ct], 0, 0, 0);
    }
    int rbase = rb + (w << 4) + g * 4;
    #pragma unroll
    for (int reg = 0; reg < 4; ++reg) {
        int rowg = rbase + reg;
        if (rowg < N) {
            #pragma unroll
            for (int ct = 0; ct < 8; ++ct)
                h1u[(size_t)rowg * 128 + ct * 16 + lrow] = (unsigned short)f2bf_bits(acc[ct][reg]);
        }
    }
}

// w[n][0..48) = y[n] @ W2 (pad-zeros to 64), via MFMA. y bf16 [n][128].
__global__ __launch_bounds__(256) void gemmW2_kernel(const unsigned short* __restrict__ yu,
                                                     const unsigned short* __restrict__ wt2,
                                                     unsigned short* __restrict__ wu, int N) {
    __shared__ uint4 xs4[1024];                 // 64 rows x 256B (bf16, XOR-swizzled)
    char* xsb = (char*)xs4;
    int t = threadIdx.x;
    int rb = blockIdx.x * 64;
    #pragma unroll
    for (int i = 0; i < 8; ++i) {
        int idx = i * 256 + t;
        int row = idx >> 5, q = idx & 31;       // q: 4-bf16 slot
        int gr = rb + row;
        uint2 v = make_uint2(0u, 0u);
        if (gr < N) v = *(const uint2*)(yu + (size_t)gr * 128 + q * 4);
        int boff = row * 256 + ((q * 8) ^ ((row & 7) << 4));
        *(uint2*)(xsb + boff) = v;
    }
    __syncthreads();
    int w = t >> 6, lane = t & 63;
    int lrow = lane & 15, g = lane >> 4;
    int sw = (lrow & 7) << 4;
    int rloc = (w << 4) + lrow;
    short8 a[4];
    #pragma unroll
    for (int kt = 0; kt < 4; ++kt)
        a[kt] = *(const short8*)(xsb + rloc * 256 + ((kt * 64 + g * 16) ^ sw));
    f32x4 acc[3];
    #pragma unroll
    for (int ct = 0; ct < 3; ++ct) acc[ct] = (f32x4){0.f, 0.f, 0.f, 0.f};
    #pragma unroll
    for (int ct = 0; ct < 3; ++ct) {
        const unsigned short* wb = wt2 + (size_t)(ct * 16 + lrow) * 128 + g * 8;
        short8 b0 = *(const short8*)(wb);
        short8 b1 = *(const short8*)(wb + 32);
        short8 b2 = *(const short8*)(wb + 64);
        short8 b3 = *(const short8*)(wb + 96);
        acc[ct] = __builtin_amdgcn_mfma_f32_16x16x32_bf16(a[0], b0, acc[ct], 0, 0, 0);
        acc[ct] = __builtin_amdgcn_mfma_f32_16x16x32_bf16(a[1], b1, acc[ct], 0, 0, 0);
        acc[ct] = __builtin_amdgcn_mfma_f32_16x16x32_bf16(a[2], b2, acc[ct], 0, 0, 0);
        acc[ct] = __builtin_amdgcn_mfma_f32_16x16x32_bf16(a[3], b3, acc[ct], 0, 0, 0);
    }
    int rbase = rb + (w << 4) + g * 4;
    #pragma unroll
    for (int reg = 0; reg < 4; ++reg) {
        int rowg = rbase + reg;
        if (rowg < N) {
            #pragma unroll
            for (int ct = 0; ct < 3; ++ct)
                wu[(size_t)rowg * 64 + ct * 16 + lrow] = (unsigned short)f2bf_bits(acc[ct][reg]);
            wu[(size_t)rowg * 64 + 48 + lrow] = 0;   // pad cols 48..63
        }
    }
}

// ---------------- gathers (one node per wave) ----------------

#define ACC8(v)  { a0 += bflo(v.x); a1 += bfhi(v.x); a2 += bflo(v.y); a3 += bfhi(v.y); \
                   a4 += bflo(v.z); a5 += bfhi(v.z); a6 += bflo(v.w); a7 += bfhi(v.w); }

// y[n] = ns * relu( (sum h1[src]) * nd + b1 ), flat [n][128] bf16.
__global__ __launch_bounds__(256) void agg1_kernel(const int* __restrict__ row_ptr, const int* __restrict__ col,
                                                   const uint4* __restrict__ h1q, const float* __restrict__ norm_dst,
                                                   const float* __restrict__ norm_src,
                                                   const float* __restrict__ b1, uint4* __restrict__ yq, int N) {
    int t = threadIdx.x;
    int wid = t >> 6, lane = t & 63;
    int g = lane >> 4, f = lane & 15;
    int n = blockIdx.x * 4 + wid;
    if (n >= N) return;
    int beg = row_ptr[n], deg = row_ptr[n + 1] - beg;
    const int* cp = col + beg;
    float a0 = 0, a1 = 0, a2 = 0, a3 = 0, a4 = 0, a5 = 0, a6 = 0, a7 = 0;
    int e = 0;
    for (; e + 8 <= deg; e += 8) {
        int s0 = cp[e + g];
        int s1 = cp[e + 4 + g];
        uint4 v0 = h1q[(size_t)s0 * 16 + f];
        uint4 v1 = h1q[(size_t)s1 * 16 + f];
        ACC8(v0); ACC8(v1);
    }
    for (; e < deg; e += 4) {
        int idx = e + g;
        if (idx < deg) {
            uint4 v = h1q[(size_t)cp[idx] * 16 + f];
            ACC8(v);
        }
    }
    a0 += __shfl_xor(a0, 16, 64); a0 += __shfl_xor(a0, 32, 64);
    a1 += __shfl_xor(a1, 16, 64); a1 += __shfl_xor(a1, 32, 64);
    a2 += __shfl_xor(a2, 16, 64); a2 += __shfl_xor(a2, 32, 64);
    a3 += __shfl_xor(a3, 16, 64); a3 += __shfl_xor(a3, 32, 64);
    a4 += __shfl_xor(a4, 16, 64); a4 += __shfl_xor(a4, 32, 64);
    a5 += __shfl_xor(a5, 16, 64); a5 += __shfl_xor(a5, 32, 64);
    a6 += __shfl_xor(a6, 16, 64); a6 += __shfl_xor(a6, 32, 64);
    a7 += __shfl_xor(a7, 16, 64); a7 += __shfl_xor(a7, 32, 64);
    if (g == 0) {
        float nd = norm_dst[n];
        float ns = norm_src[n];
        float4 bA = *(const float4*)(b1 + f * 8);
        float4 bB = *(const float4*)(b1 + f * 8 + 4);
        float o0 = ns * fmaxf(a0 * nd + bA.x, 0.f);
        float o1 = ns * fmaxf(a1 * nd + bA.y, 0.f);
        float o2 = ns * fmaxf(a2 * nd + bA.z, 0.f);
        float o3 = ns * fmaxf(a3 * nd + bA.w, 0.f);
        float o4 = ns * fmaxf(a4 * nd + bB.x, 0.f);
        float o5 = ns * fmaxf(a5 * nd + bB.y, 0.f);
        float o6 = ns * fmaxf(a6 * nd + bB.z, 0.f);
        float o7 = ns * fmaxf(a7 * nd + bB.w, 0.f);
        uint4 p;
        p.x = pack_bf2(o0, o1); p.y = pack_bf2(o2, o3);
        p.z = pack_bf2(o4, o5); p.w = pack_bf2(o6, o7);
        yq[(size_t)n * 16 + f] = p;
    }
}

// out[n][j] = (sum w[src][j]) * nd + b2[j], j<40.  w rows 128B (8 uint4).
// lane(g=lane>>3 covers 8 edges, f=lane&7 covers 8 feats).
__global__ __launch_bounds__(256) void aggZ_kernel(const int* __restrict__ row_ptr, const int* __restrict__ col,
                                                   const uint4* __restrict__ wq, const float* __restrict__ norm_dst,
                                                   const float* __restrict__ b2, float* __restrict__ out, int N) {
    int t = threadIdx.x;
    int wid = t >> 6, lane = t & 63;
    int g = lane >> 3, f = lane & 7;
    int n = blockIdx.x * 4 + wid;
    if (n >= N) return;
    int beg = row_ptr[n], deg = row_ptr[n + 1] - beg;
    const int* cp = col + beg;
    float a0 = 0, a1 = 0, a2 = 0, a3 = 0, a4 = 0, a5 = 0, a6 = 0, a7 = 0;
    int e = 0;
    for (; e + 16 <= deg; e += 16) {
        int s0 = cp[e + g];
        int s1 = cp[e + 8 + g];
        uint4 v0 = wq[(size_t)s0 * 8 + f];
        uint4 v1 = wq[(size_t)s1 * 8 + f];
        ACC8(v0); ACC8(v1);
    }
    for (; e < deg; e += 8) {
        int idx = e + g;
        if (idx < deg) {
            uint4 v = wq[(size_t)cp[idx] * 8 + f];
            ACC8(v);
        }
    }
    a0 += __shfl_xor(a0, 8, 64); a0 += __shfl_xor(a0, 16, 64); a0 += __shfl_xor(a0, 32, 64);
    a1 += __shfl_xor(a1, 8, 64); a1 += __shfl_xor(a1, 16, 64); a1 += __shfl_xor(a1, 32, 64);
    a2 += __shfl_xor(a2, 8, 64); a2 += __shfl_xor(a2, 16, 64); a2 += __shfl_xor(a2, 32, 64);
    a3 += __shfl_xor(a3, 8, 64); a3 += __shfl_xor(a3, 16, 64); a3 += __shfl_xor(a3, 32, 64);
    a4 += __shfl_xor(a4, 8, 64); a4 += __shfl_xor(a4, 16, 64); a4 += __shfl_xor(a4, 32, 64);
    a5 += __shfl_xor(a5, 8, 64); a5 += __shfl_xor(a5, 16, 64); a5 += __shfl_xor(a5, 32, 64);
    a6 += __shfl_xor(a6, 8, 64); a6 += __shfl_xor(a6, 16, 64); a6 += __shfl_xor(a6, 32, 64);
    a7 += __shfl_xor(a7, 8, 64); a7 += __shfl_xor(a7, 16, 64); a7 += __shfl_xor(a7, 32, 64);
    if (g == 0 && f < 5) {
        float nd = norm_dst[n];
        int j0 = f * 8;
        float4 bA = *(const float4*)(b2 + j0);
        float4 bB = *(const float4*)(b2 + j0 + 4);
        float* op = out + (size_t)n * 40 + j0;
        *(float4*)(op)     = make_float4(a0 * nd + bA.x, a1 * nd + bA.y, a2 * nd + bA.z, a3 * nd + bA.w);
        *(float4*)(op + 4) = make_float4(a4 * nd + bB.x, a5 * nd + bB.y, a6 * nd + bB.z, a7 * nd + bB.w);
    }
}

extern "C" void kernel_launch(void* const* d_in, const int* in_sizes, int n_in,
                              void* d_out, int out_size, void* d_ws, size_t ws_size,
                              hipStream_t stream) {
    const float* x  = (const float*)d_in[0];
    const int* src  = (const int*)d_in[1];
    const int* dst  = (const int*)d_in[2];
    const float* W1 = (const float*)d_in[3];
    const float* b1 = (const float*)d_in[4];
    const float* W2 = (const float*)d_in[5];
    const float* b2 = (const float*)d_in[6];
    float* out = (float*)d_out;

    int N = in_sizes[0] / 128;
    int E = in_sizes[1];
    int NPAD = (N + 63) & ~63;
    int NCHUNKS = (N + CHUNK - 1) >> CHUNK_SHIFT;
    int per = ((E + NSLICES - 1) / NSLICES + 3) & ~3;
    int NB = (N + 1023) / 1024;

    float* ws = (float*)d_ws;
    float* norm_src = ws;                                       // NPAD floats
    float* norm_dst = ws + NPAD;                                // NPAD floats
    int* deg_dst_i  = (int*)(ws + 2 * (size_t)NPAD);            // NPAD ints
    int* row_ptr    = (int*)(ws + 3 * (size_t)NPAD);            // N+1 ints
    int* bsum       = (int*)(ws + 4 * (size_t)NPAD);            // NB (<=64) ints
    unsigned short* wt1 = (unsigned short*)(ws + 4 * (size_t)NPAD + 64);        // 16384 bf16 (8192 fl)
    unsigned short* wt2 = (unsigned short*)(ws + 4 * (size_t)NPAD + 64 + 8192); // 6144 bf16 (3072 fl)
    int* col        = (int*)(ws + 4 * (size_t)NPAD + 64 + 8192 + 3072);         // E ints
    size_t h1_off   = ((size_t)4 * NPAD + 64 + 8192 + 3072 + E + 15) & ~(size_t)15;
    unsigned short* h1u = (unsigned short*)(ws + h1_off);       // NPAD*128 bf16 (12.8MB)
    uint4* h1q      = (uint4*)h1u;
    unsigned short* yu = h1u + (size_t)NPAD * 128;              // NPAD*128 bf16 (slot 2)
    uint4* yq       = (uint4*)yu;
    unsigned short* wu = h1u;                                   // w reuses h1 slot (NPAD*64 bf16)
    uint4* wq       = (uint4*)wu;
    unsigned int* part = (unsigned int*)h1u;                    // 16.8MB, dead before gemm1

    dim3 cgrid(NSLICES, NCHUNKS);
    wprep_kernel<<<8, 256, 0, stream>>>(W1, wt1);
    wprep2_kernel<<<3, 256, 0, stream>>>(W2, wt2);
    count_kernel<<<cgrid, 256, 0, stream>>>(src, dst, part, E, per);
    reduce_kernel<<<(N + 255) / 256, 256, 0, stream>>>(part, norm_src, norm_dst, deg_dst_i, N);
    scanA_kernel<<<NB, 256, 0, stream>>>(deg_dst_i, bsum, N);
    scanB_kernel<<<1, 64, 0, stream>>>(bsum, NB, row_ptr, N);
    scanC_kernel<<<NB, 256, 0, stream>>>(deg_dst_i, bsum, row_ptr, N);
    offsets_kernel<<<(N + 255) / 256, 256, 0, stream>>>(part, row_ptr, N);
    scatter_kernel<<<cgrid, 256, 0, stream>>>(src, dst, part, col, E, per);
    gemm1_kernel<<<(N + 63) / 64, 256, 0, stream>>>(x, norm_src, wt1, h1u, N);
    agg1_kernel<<<(N + 3) / 4, 256, 0, stream>>>(row_ptr, col, h1q, norm_dst, norm_src, b1, yq, N);
    gemmW2_kernel<<<(N + 63) / 64, 256, 0, stream>>>(yu, wt2, wu, N);
    aggZ_kernel<<<(N + 3) / 4, 256, 0, stream>>>(row_ptr, col, wq, norm_dst, b2, out, N);
}

// Round 13
// 207.381 us; speedup vs baseline: 1.5798x; 1.0038x over previous
//
#include <hip/hip_runtime.h>

// 2-layer GCN (GraphConv, norm='both') for N=50000, E=1600000, 128->128->40.
// Graph build: chunked counting sort, no global atomics.
// gemm1: MFMA bf16 -> h1 [n][128] bf16. agg1: one node/wave uint4 gather,
// unroll-16 (4 independent col+gather chains in flight). W2 commuted before
// 2nd aggregation: w = y@W2 (MFMA, 128B rows), aggZ unroll-32 -> d_out.

#define CHUNK 16384
#define CHUNK_SHIFT 14
#define NSLICES 64

typedef int iv4 __attribute__((ext_vector_type(4)));
typedef short short8 __attribute__((ext_vector_type(8)));
typedef float f32x4 __attribute__((ext_vector_type(4)));

__device__ __forceinline__ unsigned f2bf_bits(float f) {
    unsigned u = __float_as_uint(f);
    return (u + 0x7FFFu + ((u >> 16) & 1u)) >> 16;   // RNE
}
__device__ __forceinline__ unsigned pack_bf2(float a, float b) {
    return f2bf_bits(a) | (f2bf_bits(b) << 16);
}
__device__ __forceinline__ float bflo(unsigned v) { return __uint_as_float(v << 16); }
__device__ __forceinline__ float bfhi(unsigned v) { return __uint_as_float(v & 0xFFFF0000u); }

// ---------------- graph build ----------------

__global__ __launch_bounds__(256) void count_kernel(const int* __restrict__ src, const int* __restrict__ dst,
                                                    unsigned int* __restrict__ part, int E, int per) {
    __shared__ unsigned int h[CHUNK];
    int c = blockIdx.y, s = blockIdx.x, t = threadIdx.x;
    #pragma unroll
    for (int i = 0; i < CHUNK / 256; ++i) h[i * 256 + t] = 0;
    __syncthreads();
    int base = c << CHUNK_SHIFT;
    int beg = s * per;
    int end = min(E, beg + per);
    int nv = (end - beg) >> 2;
    const iv4* d4 = (const iv4*)(dst + beg);
    const iv4* s4 = (const iv4*)(src + beg);
    for (int i = t; i < nv; i += 256) {
        iv4 dv = __builtin_nontemporal_load(d4 + i);
        iv4 sv = __builtin_nontemporal_load(s4 + i);
        int x;
        x = dv.x - base; if ((unsigned)x < CHUNK) atomicAdd(&h[x], 1u);
        x = dv.y - base; if ((unsigned)x < CHUNK) atomicAdd(&h[x], 1u);
        x = dv.z - base; if ((unsigned)x < CHUNK) atomicAdd(&h[x], 1u);
        x = dv.w - base; if ((unsigned)x < CHUNK) atomicAdd(&h[x], 1u);
        x = sv.x - base; if ((unsigned)x < CHUNK) atomicAdd(&h[x], 0x10000u);
        x = sv.y - base; if ((unsigned)x < CHUNK) atomicAdd(&h[x], 0x10000u);
        x = sv.z - base; if ((unsigned)x < CHUNK) atomicAdd(&h[x], 0x10000u);
        x = sv.w - base; if ((unsigned)x < CHUNK) atomicAdd(&h[x], 0x10000u);
    }
    for (int e = beg + (nv << 2) + t; e < end; e += 256) {
        int x = dst[e] - base; if ((unsigned)x < CHUNK) atomicAdd(&h[x], 1u);
        x = src[e] - base;     if ((unsigned)x < CHUNK) atomicAdd(&h[x], 0x10000u);
    }
    __syncthreads();
    unsigned int* out = part + (((size_t)(c * NSLICES + s)) << CHUNK_SHIFT);
    #pragma unroll
    for (int i = 0; i < CHUNK / 256; ++i) __builtin_nontemporal_store(h[i * 256 + t], out + i * 256 + t);
}

__global__ __launch_bounds__(256) void reduce_kernel(const unsigned int* __restrict__ part,
                                                     float* __restrict__ norm_src, float* __restrict__ norm_dst,
                                                     int* __restrict__ deg_dst_i, int N) {
    int d = blockIdx.x * 256 + threadIdx.x;
    if (d >= N) return;
    int c = d >> CHUNK_SHIFT, idx = d & (CHUNK - 1);
    const unsigned int* p = part + (((size_t)c * NSLICES) << CHUNK_SHIFT) + idx;
    unsigned int dsum = 0, ssum = 0;
    #pragma unroll
    for (int s = 0; s < NSLICES; ++s) {
        unsigned int v = __builtin_nontemporal_load(p + ((size_t)s << CHUNK_SHIFT));
        dsum += v & 0xFFFFu;
        ssum += v >> 16;
    }
    deg_dst_i[d] = (int)dsum;
    norm_src[d] = rsqrtf(fmaxf((float)ssum, 1.0f));
    norm_dst[d] = rsqrtf(fmaxf((float)dsum, 1.0f));
}

__global__ __launch_bounds__(256) void scanA_kernel(const int* __restrict__ deg, int* __restrict__ bsum, int N) {
    __shared__ int wsum[4];
    int b = blockIdx.x, t = threadIdx.x, lane = t & 63, wid = t >> 6;
    int i0 = b * 1024 + t * 4;
    int s = 0;
    if (i0 + 3 < N) {
        int4 v = *(const int4*)(deg + i0);
        s = v.x + v.y + v.z + v.w;
    } else {
        for (int k = 0; k < 4; ++k) { int i = i0 + k; if (i < N) s += deg[i]; }
    }
    #pragma unroll
    for (int off = 32; off; off >>= 1) s += __shfl_down(s, off, 64);
    if (lane == 0) wsum[wid] = s;
    __syncthreads();
    if (t == 0) bsum[b] = wsum[0] + wsum[1] + wsum[2] + wsum[3];
}

__global__ __launch_bounds__(64) void scanB_kernel(int* __restrict__ bsum, int NB,
                                                   int* __restrict__ row_ptr, int N) {
    int t = threadIdx.x;
    int v = (t < NB) ? bsum[t] : 0;
    int x = v;
    #pragma unroll
    for (int off = 1; off < 64; off <<= 1) {
        int y = __shfl_up(x, off, 64);
        if (t >= off) x += y;
    }
    if (t < NB) bsum[t] = x - v;
    if (t == 63) row_ptr[N] = x;
}

__global__ __launch_bounds__(256) void scanC_kernel(const int* __restrict__ deg, const int* __restrict__ bsum,
                                                    int* __restrict__ row_ptr, int N) {
    __shared__ int wsum[4];
    int b = blockIdx.x, t = threadIdx.x, lane = t & 63, wid = t >> 6;
    int i0 = b * 1024 + t * 4;
    int4 v = make_int4(0, 0, 0, 0);
    if (i0 + 3 < N) v = *(const int4*)(deg + i0);
    else {
        v.x = (i0 < N) ? deg[i0] : 0;
        v.y = (i0 + 1 < N) ? deg[i0 + 1] : 0;
        v.z = (i0 + 2 < N) ? deg[i0 + 2] : 0;
        v.w = (i0 + 3 < N) ? deg[i0 + 3] : 0;
    }
    int tsum = v.x + v.y + v.z + v.w;
    int x = tsum;
    #pragma unroll
    for (int off = 1; off < 64; off <<= 1) {
        int y = __shfl_up(x, off, 64);
        if (lane >= off) x += y;
    }
    if (lane == 63) wsum[wid] = x;
    __syncthreads();
    int woff = 0;
    for (int k = 0; k < wid; ++k) woff += wsum[k];
    int base = bsum[b] + woff + (x - tsum);
    int e0 = base, e1 = e0 + v.x, e2 = e1 + v.y, e3 = e2 + v.z;
    if (i0 + 3 < N) *(int4*)(row_ptr + i0) = make_int4(e0, e1, e2, e3);
    else {
        if (i0 < N) row_ptr[i0] = e0;
        if (i0 + 1 < N) row_ptr[i0 + 1] = e1;
        if (i0 + 2 < N) row_ptr[i0 + 2] = e2;
        if (i0 + 3 < N) row_ptr[i0 + 3] = e3;
    }
}

__global__ __launch_bounds__(256) void offsets_kernel(unsigned int* __restrict__ part,
                                                      const int* __restrict__ row_ptr, int N) {
    int d = blockIdx.x * 256 + threadIdx.x;
    if (d >= N) return;
    int c = d >> CHUNK_SHIFT, idx = d & (CHUNK - 1);
    unsigned int* p = part + (((size_t)c * NSLICES) << CHUNK_SHIFT) + idx;
    unsigned int running = (unsigned int)row_ptr[d];
    #pragma unroll
    for (int s = 0; s < NSLICES; ++s) {
        unsigned int v = __builtin_nontemporal_load(p + ((size_t)s << CHUNK_SHIFT));
        __builtin_nontemporal_store(running, p + ((size_t)s << CHUNK_SHIFT));
        running += v & 0xFFFFu;
    }
}

__global__ __launch_bounds__(256) void scatter_kernel(const int* __restrict__ src, const int* __restrict__ dst,
                                                      const unsigned int* __restrict__ cum,
                                                      int* __restrict__ col, int E, int per) {
    __shared__ int cur[CHUNK];
    int c = blockIdx.y, s = blockIdx.x, t = threadIdx.x;
    const unsigned int* cc = cum + (((size_t)(c * NSLICES + s)) << CHUNK_SHIFT);
    #pragma unroll
    for (int i = 0; i < CHUNK / 256; ++i) cur[i * 256 + t] = (int)__builtin_nontemporal_load(cc + i * 256 + t);
    __syncthreads();
    int base = c << CHUNK_SHIFT;
    int beg = s * per;
    int end = min(E, beg + per);
    int nv = (end - beg) >> 2;
    const iv4* d4 = (const iv4*)(dst + beg);
    const iv4* s4 = (const iv4*)(src + beg);
    for (int i = t; i < nv; i += 256) {
        iv4 dv = __builtin_nontemporal_load(d4 + i);
        iv4 sv = __builtin_nontemporal_load(s4 + i);
        int x;
        x = dv.x - base; if ((unsigned)x < CHUNK) col[atomicAdd(&cur[x], 1)] = sv.x;
        x = dv.y - base; if ((unsigned)x < CHUNK) col[atomicAdd(&cur[x], 1)] = sv.y;
        x = dv.z - base; if ((unsigned)x < CHUNK) col[atomicAdd(&cur[x], 1)] = sv.z;
        x = dv.w - base; if ((unsigned)x < CHUNK) col[atomicAdd(&cur[x], 1)] = sv.w;
    }
    for (int e = beg + (nv << 2) + t; e < end; e += 256) {
        int x = dst[e] - base;
        if ((unsigned)x < CHUNK) col[atomicAdd(&cur[x], 1)] = src[e];
    }
}

// ---------------- dense layers ----------------

// wt[c][k] = bf16(W1[k][c]), 128x128. Grid 8 x 256 threads.
__global__ __launch_bounds__(256) void wprep_kernel(const float* __restrict__ W, unsigned short* __restrict__ wt) {
    int tid = blockIdx.x * 256 + threadIdx.x;   // 0..2047
    int c = tid & 127, kg = tid >> 7;           // kg 0..15
    unsigned p[4];
    #pragma unroll
    for (int j = 0; j < 4; ++j) {
        float v0 = W[(kg * 8 + 2 * j) * 128 + c];
        float v1 = W[(kg * 8 + 2 * j + 1) * 128 + c];
        p[j] = pack_bf2(v0, v1);
    }
    *(uint4*)(wt + (size_t)c * 128 + kg * 8) = make_uint4(p[0], p[1], p[2], p[3]);
}

// wt2[c][k] = bf16(W2[k][c]) for c<40, zeros for 40<=c<48. Grid 3 x 256.
__global__ __launch_bounds__(256) void wprep2_kernel(const float* __restrict__ W2, unsigned short* __restrict__ wt2) {
    int tid = blockIdx.x * 256 + threadIdx.x;   // 0..767
    int c = tid >> 4, kg = tid & 15;            // c 0..47, kg 0..15
    unsigned p[4];
    #pragma unroll
    for (int j = 0; j < 4; ++j) {
        float v0 = (c < 40) ? W2[(kg * 8 + 2 * j) * 40 + c] : 0.f;
        float v1 = (c < 40) ? W2[(kg * 8 + 2 * j + 1) * 40 + c] : 0.f;
        p[j] = pack_bf2(v0, v1);
    }
    *(uint4*)(wt2 + (size_t)c * 128 + kg * 8) = make_uint4(p[0], p[1], p[2], p[3]);
}

// h1[n][j] = bf16( (ns*x)bf16 @ W1 ) via mfma_f32_16x16x32_bf16, flat [n][128].
__global__ __launch_bounds__(256) void gemm1_kernel(const float* __restrict__ x, const float* __restrict__ norm,
                                                    const unsigned short* __restrict__ wt,
                                                    unsigned short* __restrict__ h1u, int N) {
    __shared__ uint4 xs4[1024];                 // 64 rows x 256B (bf16, XOR-swizzled)
    char* xsb = (char*)xs4;
    int t = threadIdx.x;
    int rb = blockIdx.x * 64;
    #pragma unroll
    for (int i = 0; i < 8; ++i) {
        int idx = i * 256 + t;
        int row = idx >> 5, k4 = (idx & 31) << 2;
        int gr = rb + row;
        float4 v = make_float4(0.f, 0.f, 0.f, 0.f);
        if (gr < N) {
            v = *(const float4*)(x + (size_t)gr * 128 + k4);
            float nm = norm[gr];
            v.x *= nm; v.y *= nm; v.z *= nm; v.w *= nm;
        }
        int boff = row * 256 + ((k4 * 2) ^ ((row & 7) << 4));
        *(uint2*)(xsb + boff) = make_uint2(pack_bf2(v.x, v.y), pack_bf2(v.z, v.w));
    }
    __syncthreads();
    int w = t >> 6, lane = t & 63;
    int lrow = lane & 15, g = lane >> 4;
    int sw = (lrow & 7) << 4;
    int rloc = (w << 4) + lrow;
    short8 a[4];
    #pragma unroll
    for (int kt = 0; kt < 4; ++kt)
        a[kt] = *(const short8*)(xsb + rloc * 256 + ((kt * 64 + g * 16) ^ sw));
    f32x4 acc[8];
    #pragma unroll
    for (int ct = 0; ct < 8; ++ct) acc[ct] = (f32x4){0.f, 0.f, 0.f, 0.f};
    #pragma unroll
    for (int ct = 0; ct < 8; ++ct) {
        const unsigned short* wb = wt + (size_t)(ct * 16 + lrow) * 128 + g * 8;
        short8 b0 = *(const short8*)(wb);
        short8 b1 = *(const short8*)(wb + 32);
        short8 b2 = *(const short8*)(wb + 64);
        short8 b3 = *(const short8*)(wb + 96);
        acc[ct] = __builtin_amdgcn_mfma_f32_16x16x32_bf16(a[0], b0, acc[ct], 0, 0, 0);
        acc[ct] = __builtin_amdgcn_mfma_f32_16x16x32_bf16(a[1], b1, acc[ct], 0, 0, 0);
        acc[ct] = __builtin_amdgcn_mfma_f32_16x16x32_bf16(a[2], b2, acc[ct], 0, 0, 0);
        acc[ct] = __builtin_amdgcn_mfma_f32_16x16x32_bf16(a[3], b3, acc[ct], 0, 0, 0);
    }
    int rbase = rb + (w << 4) + g * 4;
    #pragma unroll
    for (int reg = 0; reg < 4; ++reg) {
        int rowg = rbase + reg;
        if (rowg < N) {
            #pragma unroll
            for (int ct = 0; ct < 8; ++ct)
                h1u[(size_t)rowg * 128 + ct * 16 + lrow] = (unsigned short)f2bf_bits(acc[ct][reg]);
        }
    }
}

// w[n][0..48) = y[n] @ W2 (pad-zeros to 64), via MFMA. y bf16 [n][128].
__global__ __launch_bounds__(256) void gemmW2_kernel(const unsigned short* __restrict__ yu,
                                                     const unsigned short* __restrict__ wt2,
                                                     unsigned short* __restrict__ wu, int N) {
    __shared__ uint4 xs4[1024];                 // 64 rows x 256B (bf16, XOR-swizzled)
    char* xsb = (char*)xs4;
    int t = threadIdx.x;
    int rb = blockIdx.x * 64;
    #pragma unroll
    for (int i = 0; i < 8; ++i) {
        int idx = i * 256 + t;
        int row = idx >> 5, q = idx & 31;       // q: 4-bf16 slot
        int gr = rb + row;
        uint2 v = make_uint2(0u, 0u);
        if (gr < N) v = *(const uint2*)(yu + (size_t)gr * 128 + q * 4);
        int boff = row * 256 + ((q * 8) ^ ((row & 7) << 4));
        *(uint2*)(xsb + boff) = v;
    }
    __syncthreads();
    int w = t >> 6, lane = t & 63;
    int lrow = lane & 15, g = lane >> 4;
    int sw = (lrow & 7) << 4;
    int rloc = (w << 4) + lrow;
    short8 a[4];
    #pragma unroll
    for (int kt = 0; kt < 4; ++kt)
        a[kt] = *(const short8*)(xsb + rloc * 256 + ((kt * 64 + g * 16) ^ sw));
    f32x4 acc[3];
    #pragma unroll
    for (int ct = 0; ct < 3; ++ct) acc[ct] = (f32x4){0.f, 0.f, 0.f, 0.f};
    #pragma unroll
    for (int ct = 0; ct < 3; ++ct) {
        const unsigned short* wb = wt2 + (size_t)(ct * 16 + lrow) * 128 + g * 8;
        short8 b0 = *(const short8*)(wb);
        short8 b1 = *(const short8*)(wb + 32);
        short8 b2 = *(const short8*)(wb + 64);
        short8 b3 = *(const short8*)(wb + 96);
        acc[ct] = __builtin_amdgcn_mfma_f32_16x16x32_bf16(a[0], b0, acc[ct], 0, 0, 0);
        acc[ct] = __builtin_amdgcn_mfma_f32_16x16x32_bf16(a[1], b1, acc[ct], 0, 0, 0);
        acc[ct] = __builtin_amdgcn_mfma_f32_16x16x32_bf16(a[2], b2, acc[ct], 0, 0, 0);
        acc[ct] = __builtin_amdgcn_mfma_f32_16x16x32_bf16(a[3], b3, acc[ct], 0, 0, 0);
    }
    int rbase = rb + (w << 4) + g * 4;
    #pragma unroll
    for (int reg = 0; reg < 4; ++reg) {
        int rowg = rbase + reg;
        if (rowg < N) {
            #pragma unroll
            for (int ct = 0; ct < 3; ++ct)
                wu[(size_t)rowg * 64 + ct * 16 + lrow] = (unsigned short)f2bf_bits(acc[ct][reg]);
            wu[(size_t)rowg * 64 + 48 + lrow] = 0;   // pad cols 48..63
        }
    }
}

// ---------------- gathers (one node per wave) ----------------

#define ACC8(v)  { a0 += bflo(v.x); a1 += bfhi(v.x); a2 += bflo(v.y); a3 += bfhi(v.y); \
                   a4 += bflo(v.z); a5 += bfhi(v.z); a6 += bflo(v.w); a7 += bfhi(v.w); }

// y[n] = ns * relu( (sum h1[src]) * nd + b1 ), flat [n][128] bf16.
// Unroll-16: 4 independent col-load->gather chains in flight.
__global__ __launch_bounds__(256) void agg1_kernel(const int* __restrict__ row_ptr, const int* __restrict__ col,
                                                   const uint4* __restrict__ h1q, const float* __restrict__ norm_dst,
                                                   const float* __restrict__ norm_src,
                                                   const float* __restrict__ b1, uint4* __restrict__ yq, int N) {
    int t = threadIdx.x;
    int wid = t >> 6, lane = t & 63;
    int g = lane >> 4, f = lane & 15;
    int n = blockIdx.x * 4 + wid;
    if (n >= N) return;
    int beg = row_ptr[n], deg = row_ptr[n + 1] - beg;
    const int* cp = col + beg;
    float a0 = 0, a1 = 0, a2 = 0, a3 = 0, a4 = 0, a5 = 0, a6 = 0, a7 = 0;
    int e = 0;
    for (; e + 16 <= deg; e += 16) {
        int s0 = cp[e + g];
        int s1 = cp[e + 4 + g];
        int s2 = cp[e + 8 + g];
        int s3 = cp[e + 12 + g];
        uint4 v0 = h1q[(size_t)s0 * 16 + f];
        uint4 v1 = h1q[(size_t)s1 * 16 + f];
        uint4 v2 = h1q[(size_t)s2 * 16 + f];
        uint4 v3 = h1q[(size_t)s3 * 16 + f];
        ACC8(v0); ACC8(v1); ACC8(v2); ACC8(v3);
    }
    for (; e < deg; e += 4) {
        int idx = e + g;
        if (idx < deg) {
            uint4 v = h1q[(size_t)cp[idx] * 16 + f];
            ACC8(v);
        }
    }
    a0 += __shfl_xor(a0, 16, 64); a0 += __shfl_xor(a0, 32, 64);
    a1 += __shfl_xor(a1, 16, 64); a1 += __shfl_xor(a1, 32, 64);
    a2 += __shfl_xor(a2, 16, 64); a2 += __shfl_xor(a2, 32, 64);
    a3 += __shfl_xor(a3, 16, 64); a3 += __shfl_xor(a3, 32, 64);
    a4 += __shfl_xor(a4, 16, 64); a4 += __shfl_xor(a4, 32, 64);
    a5 += __shfl_xor(a5, 16, 64); a5 += __shfl_xor(a5, 32, 64);
    a6 += __shfl_xor(a6, 16, 64); a6 += __shfl_xor(a6, 32, 64);
    a7 += __shfl_xor(a7, 16, 64); a7 += __shfl_xor(a7, 32, 64);
    if (g == 0) {
        float nd = norm_dst[n];
        float ns = norm_src[n];
        float4 bA = *(const float4*)(b1 + f * 8);
        float4 bB = *(const float4*)(b1 + f * 8 + 4);
        float o0 = ns * fmaxf(a0 * nd + bA.x, 0.f);
        float o1 = ns * fmaxf(a1 * nd + bA.y, 0.f);
        float o2 = ns * fmaxf(a2 * nd + bA.z, 0.f);
        float o3 = ns * fmaxf(a3 * nd + bA.w, 0.f);
        float o4 = ns * fmaxf(a4 * nd + bB.x, 0.f);
        float o5 = ns * fmaxf(a5 * nd + bB.y, 0.f);
        float o6 = ns * fmaxf(a6 * nd + bB.z, 0.f);
        float o7 = ns * fmaxf(a7 * nd + bB.w, 0.f);
        uint4 p;
        p.x = pack_bf2(o0, o1); p.y = pack_bf2(o2, o3);
        p.z = pack_bf2(o4, o5); p.w = pack_bf2(o6, o7);
        yq[(size_t)n * 16 + f] = p;
    }
}

// out[n][j] = (sum w[src][j]) * nd + b2[j], j<40.  w rows 128B (8 uint4).
// lane(g=lane>>3 covers 8 edges, f=lane&7). Unroll-32: 4 chains in flight.
__global__ __launch_bounds__(256) void aggZ_kernel(const int* __restrict__ row_ptr, const int* __restrict__ col,
                                                   const uint4* __restrict__ wq, const float* __restrict__ norm_dst,
                                                   const float* __restrict__ b2, float* __restrict__ out, int N) {
    int t = threadIdx.x;
    int wid = t >> 6, lane = t & 63;
    int g = lane >> 3, f = lane & 7;
    int n = blockIdx.x * 4 + wid;
    if (n >= N) return;
    int beg = row_ptr[n], deg = row_ptr[n + 1] - beg;
    const int* cp = col + beg;
    float a0 = 0, a1 = 0, a2 = 0, a3 = 0, a4 = 0, a5 = 0, a6 = 0, a7 = 0;
    int e = 0;
    for (; e + 32 <= deg; e += 32) {
        int s0 = cp[e + g];
        int s1 = cp[e + 8 + g];
        int s2 = cp[e + 16 + g];
        int s3 = cp[e + 24 + g];
        uint4 v0 = wq[(size_t)s0 * 8 + f];
        uint4 v1 = wq[(size_t)s1 * 8 + f];
        uint4 v2 = wq[(size_t)s2 * 8 + f];
        uint4 v3 = wq[(size_t)s3 * 8 + f];
        ACC8(v0); ACC8(v1); ACC8(v2); ACC8(v3);
    }
    for (; e < deg; e += 8) {
        int idx = e + g;
        if (idx < deg) {
            uint4 v = wq[(size_t)cp[idx] * 8 + f];
            ACC8(v);
        }
    }
    a0 += __shfl_xor(a0, 8, 64); a0 += __shfl_xor(a0, 16, 64); a0 += __shfl_xor(a0, 32, 64);
    a1 += __shfl_xor(a1, 8, 64); a1 += __shfl_xor(a1, 16, 64); a1 += __shfl_xor(a1, 32, 64);
    a2 += __shfl_xor(a2, 8, 64); a2 += __shfl_xor(a2, 16, 64); a2 += __shfl_xor(a2, 32, 64);
    a3 += __shfl_xor(a3, 8, 64); a3 += __shfl_xor(a3, 16, 64); a3 += __shfl_xor(a3, 32, 64);
    a4 += __shfl_xor(a4, 8, 64); a4 += __shfl_xor(a4, 16, 64); a4 += __shfl_xor(a4, 32, 64);
    a5 += __shfl_xor(a5, 8, 64); a5 += __shfl_xor(a5, 16, 64); a5 += __shfl_xor(a5, 32, 64);
    a6 += __shfl_xor(a6, 8, 64); a6 += __shfl_xor(a6, 16, 64); a6 += __shfl_xor(a6, 32, 64);
    a7 += __shfl_xor(a7, 8, 64); a7 += __shfl_xor(a7, 16, 64); a7 += __shfl_xor(a7, 32, 64);
    if (g == 0 && f < 5) {
        float nd = norm_dst[n];
        int j0 = f * 8;
        float4 bA = *(const float4*)(b2 + j0);
        float4 bB = *(const float4*)(b2 + j0 + 4);
        float* op = out + (size_t)n * 40 + j0;
        *(float4*)(op)     = make_float4(a0 * nd + bA.x, a1 * nd + bA.y, a2 * nd + bA.z, a3 * nd + bA.w);
        *(float4*)(op + 4) = make_float4(a4 * nd + bB.x, a5 * nd + bB.y, a6 * nd + bB.z, a7 * nd + bB.w);
    }
}

extern "C" void kernel_launch(void* const* d_in, const int* in_sizes, int n_in,
                              void* d_out, int out_size, void* d_ws, size_t ws_size,
                              hipStream_t stream) {
    const float* x  = (const float*)d_in[0];
    const int* src  = (const int*)d_in[1];
    const int* dst  = (const int*)d_in[2];
    const float* W1 = (const float*)d_in[3];
    const float* b1 = (const float*)d_in[4];
    const float* W2 = (const float*)d_in[5];
    const float* b2 = (const float*)d_in[6];
    float* out = (float*)d_out;

    int N = in_sizes[0] / 128;
    int E = in_sizes[1];
    int NPAD = (N + 63) & ~63;
    int NCHUNKS = (N + CHUNK - 1) >> CHUNK_SHIFT;
    int per = ((E + NSLICES - 1) / NSLICES + 3) & ~3;
    int NB = (N + 1023) / 1024;

    float* ws = (float*)d_ws;
    float* norm_src = ws;                                       // NPAD floats
    float* norm_dst = ws + NPAD;                                // NPAD floats
    int* deg_dst_i  = (int*)(ws + 2 * (size_t)NPAD);            // NPAD ints
    int* row_ptr    = (int*)(ws + 3 * (size_t)NPAD);            // N+1 ints
    int* bsum       = (int*)(ws + 4 * (size_t)NPAD);            // NB (<=64) ints
    unsigned short* wt1 = (unsigned short*)(ws + 4 * (size_t)NPAD + 64);        // 16384 bf16 (8192 fl)
    unsigned short* wt2 = (unsigned short*)(ws + 4 * (size_t)NPAD + 64 + 8192); // 6144 bf16 (3072 fl)
    int* col        = (int*)(ws + 4 * (size_t)NPAD + 64 + 8192 + 3072);         // E ints
    size_t h1_off   = ((size_t)4 * NPAD + 64 + 8192 + 3072 + E + 15) & ~(size_t)15;
    unsigned short* h1u = (unsigned short*)(ws + h1_off);       // NPAD*128 bf16 (12.8MB)
    uint4* h1q      = (uint4*)h1u;
    unsigned short* yu = h1u + (size_t)NPAD * 128;              // NPAD*128 bf16 (slot 2)
    uint4* yq       = (uint4*)yu;
    unsigned short* wu = h1u;                                   // w reuses h1 slot (NPAD*64 bf16)
    uint4* wq       = (uint4*)wu;
    unsigned int* part = (unsigned int*)h1u;                    // 16.8MB, dead before gemm1

    dim3 cgrid(NSLICES, NCHUNKS);
    wprep_kernel<<<8, 256, 0, stream>>>(W1, wt1);
    wprep2_kernel<<<3, 256, 0, stream>>>(W2, wt2);
    count_kernel<<<cgrid, 256, 0, stream>>>(src, dst, part, E, per);
    reduce_kernel<<<(N + 255) / 256, 256, 0, stream>>>(part, norm_src, norm_dst, deg_dst_i, N);
    scanA_kernel<<<NB, 256, 0, stream>>>(deg_dst_i, bsum, N);
    scanB_kernel<<<1, 64, 0, stream>>>(bsum, NB, row_ptr, N);
    scanC_kernel<<<NB, 256, 0, stream>>>(deg_dst_i, bsum, row_ptr, N);
    offsets_kernel<<<(N + 255) / 256, 256, 0, stream>>>(part, row_ptr, N);
    scatter_kernel<<<cgrid, 256, 0, stream>>>(src, dst, part, col, E, per);
    gemm1_kernel<<<(N + 63) / 64, 256, 0, stream>>>(x, norm_src, wt1, h1u, N);
    agg1_kernel<<<(N + 3) / 4, 256, 0, stream>>>(row_ptr, col, h1q, norm_dst, norm_src, b1, yq, N);
    gemmW2_kernel<<<(N + 63) / 64, 256, 0, stream>>>(yu, wt2, wu, N);
    aggZ_kernel<<<(N + 3) / 4, 256, 0, stream>>>(row_ptr, col, wq, norm_dst, b2, out, N);
}

// Round 14
// 199.248 us; speedup vs baseline: 1.6442x; 1.0408x over previous
//
#include <hip/hip_runtime.h>

// 2-layer GCN (GraphConv, norm='both') for N=50000, E=1600000, 128->128->40.
// Graph build: chunked counting sort, no global atomics (fused scans).
// gemm1: MFMA bf16 -> h1 [n][128] bf16. agg1: one node/wave uint4 gather.
// W2 commuted before 2nd aggregation: w = y@W2 (80B rows, no padding),
// aggZ gathers w (f<5 lanes, zero waste) -> d_out.

#define CHUNK 16384
#define CHUNK_SHIFT 14
#define NSLICES 64

typedef int iv4 __attribute__((ext_vector_type(4)));
typedef short short8 __attribute__((ext_vector_type(8)));
typedef float f32x4 __attribute__((ext_vector_type(4)));

__device__ __forceinline__ unsigned f2bf_bits(float f) {
    unsigned u = __float_as_uint(f);
    return (u + 0x7FFFu + ((u >> 16) & 1u)) >> 16;   // RNE
}
__device__ __forceinline__ unsigned pack_bf2(float a, float b) {
    return f2bf_bits(a) | (f2bf_bits(b) << 16);
}
__device__ __forceinline__ float bflo(unsigned v) { return __uint_as_float(v << 16); }
__device__ __forceinline__ float bfhi(unsigned v) { return __uint_as_float(v & 0xFFFF0000u); }

// ---------------- graph build ----------------

__global__ __launch_bounds__(256) void count_kernel(const int* __restrict__ src, const int* __restrict__ dst,
                                                    unsigned int* __restrict__ part, int E, int per) {
    __shared__ unsigned int h[CHUNK];
    int c = blockIdx.y, s = blockIdx.x, t = threadIdx.x;
    #pragma unroll
    for (int i = 0; i < CHUNK / 256; ++i) h[i * 256 + t] = 0;
    __syncthreads();
    int base = c << CHUNK_SHIFT;
    int beg = s * per;
    int end = min(E, beg + per);
    int nv = (end - beg) >> 2;
    const iv4* d4 = (const iv4*)(dst + beg);
    const iv4* s4 = (const iv4*)(src + beg);
    for (int i = t; i < nv; i += 256) {
        iv4 dv = __builtin_nontemporal_load(d4 + i);
        iv4 sv = __builtin_nontemporal_load(s4 + i);
        int x;
        x = dv.x - base; if ((unsigned)x < CHUNK) atomicAdd(&h[x], 1u);
        x = dv.y - base; if ((unsigned)x < CHUNK) atomicAdd(&h[x], 1u);
        x = dv.z - base; if ((unsigned)x < CHUNK) atomicAdd(&h[x], 1u);
        x = dv.w - base; if ((unsigned)x < CHUNK) atomicAdd(&h[x], 1u);
        x = sv.x - base; if ((unsigned)x < CHUNK) atomicAdd(&h[x], 0x10000u);
        x = sv.y - base; if ((unsigned)x < CHUNK) atomicAdd(&h[x], 0x10000u);
        x = sv.z - base; if ((unsigned)x < CHUNK) atomicAdd(&h[x], 0x10000u);
        x = sv.w - base; if ((unsigned)x < CHUNK) atomicAdd(&h[x], 0x10000u);
    }
    for (int e = beg + (nv << 2) + t; e < end; e += 256) {
        int x = dst[e] - base; if ((unsigned)x < CHUNK) atomicAdd(&h[x], 1u);
        x = src[e] - base;     if ((unsigned)x < CHUNK) atomicAdd(&h[x], 0x10000u);
    }
    __syncthreads();
    unsigned int* out = part + (((size_t)(c * NSLICES + s)) << CHUNK_SHIFT);
    #pragma unroll
    for (int i = 0; i < CHUNK / 256; ++i) __builtin_nontemporal_store(h[i * 256 + t], out + i * 256 + t);
}

// Per node: sum slice counts -> deg, norms; block-reduce deg -> bsum[block].
__global__ __launch_bounds__(256) void reduce_kernel(const unsigned int* __restrict__ part,
                                                     float* __restrict__ norm_src, float* __restrict__ norm_dst,
                                                     int* __restrict__ deg_dst_i, int* __restrict__ bsum, int N) {
    __shared__ int wsum[4];
    int b = blockIdx.x, t = threadIdx.x, lane = t & 63, wid = t >> 6;
    int d = b * 256 + t;
    unsigned int dsum = 0, ssum = 0;
    if (d < N) {
        int c = d >> CHUNK_SHIFT, idx = d & (CHUNK - 1);
        const unsigned int* p = part + (((size_t)c * NSLICES) << CHUNK_SHIFT) + idx;
        #pragma unroll
        for (int s = 0; s < NSLICES; ++s) {
            unsigned int v = __builtin_nontemporal_load(p + ((size_t)s << CHUNK_SHIFT));
            dsum += v & 0xFFFFu;
            ssum += v >> 16;
        }
        deg_dst_i[d] = (int)dsum;
        norm_src[d] = rsqrtf(fmaxf((float)ssum, 1.0f));
        norm_dst[d] = rsqrtf(fmaxf((float)dsum, 1.0f));
    }
    int s = (int)dsum;
    #pragma unroll
    for (int off = 32; off; off >>= 1) s += __shfl_down(s, off, 64);
    if (lane == 0) wsum[wid] = s;
    __syncthreads();
    if (t == 0) bsum[b] = wsum[0] + wsum[1] + wsum[2] + wsum[3];
}

// Single block: exclusive scan of bsum[0..NB) (NB<=256), row_ptr[N]=total.
__global__ __launch_bounds__(256) void scanB_kernel(int* __restrict__ bsum, int NB,
                                                    int* __restrict__ row_ptr, int N) {
    __shared__ int wsum[4];
    int t = threadIdx.x, lane = t & 63, wid = t >> 6;
    int v = (t < NB) ? bsum[t] : 0;
    int x = v;
    #pragma unroll
    for (int off = 1; off < 64; off <<= 1) {
        int y = __shfl_up(x, off, 64);
        if (lane >= off) x += y;
    }
    if (lane == 63) wsum[wid] = x;
    __syncthreads();
    int woff = 0;
    for (int k = 0; k < wid; ++k) woff += wsum[k];
    if (t < NB) bsum[t] = woff + x - v;
    if (t == 255) row_ptr[N] = woff + x;
}

// Per node: block-exclusive-scan of deg + bsum[b] -> row_ptr, then slice cursors.
__global__ __launch_bounds__(256) void offsets_kernel(unsigned int* __restrict__ part,
                                                      const int* __restrict__ deg, const int* __restrict__ bsum,
                                                      int* __restrict__ row_ptr, int N) {
    __shared__ int wsum[4];
    int b = blockIdx.x, t = threadIdx.x, lane = t & 63, wid = t >> 6;
    int d = b * 256 + t;
    int v = (d < N) ? deg[d] : 0;
    int x = v;
    #pragma unroll
    for (int off = 1; off < 64; off <<= 1) {
        int y = __shfl_up(x, off, 64);
        if (lane >= off) x += y;
    }
    if (lane == 63) wsum[wid] = x;
    __syncthreads();
    int woff = 0;
    for (int k = 0; k < wid; ++k) woff += wsum[k];
    int excl = bsum[b] + woff + (x - v);
    if (d < N) {
        row_ptr[d] = excl;
        int c = d >> CHUNK_SHIFT, idx = d & (CHUNK - 1);
        unsigned int* p = part + (((size_t)c * NSLICES) << CHUNK_SHIFT) + idx;
        unsigned int running = (unsigned int)excl;
        #pragma unroll
        for (int s = 0; s < NSLICES; ++s) {
            unsigned int pv = __builtin_nontemporal_load(p + ((size_t)s << CHUNK_SHIFT));
            __builtin_nontemporal_store(running, p + ((size_t)s << CHUNK_SHIFT));
            running += pv & 0xFFFFu;
        }
    }
}

__global__ __launch_bounds__(256) void scatter_kernel(const int* __restrict__ src, const int* __restrict__ dst,
                                                      const unsigned int* __restrict__ cum,
                                                      int* __restrict__ col, int E, int per) {
    __shared__ int cur[CHUNK];
    int c = blockIdx.y, s = blockIdx.x, t = threadIdx.x;
    const unsigned int* cc = cum + (((size_t)(c * NSLICES + s)) << CHUNK_SHIFT);
    #pragma unroll
    for (int i = 0; i < CHUNK / 256; ++i) cur[i * 256 + t] = (int)__builtin_nontemporal_load(cc + i * 256 + t);
    __syncthreads();
    int base = c << CHUNK_SHIFT;
    int beg = s * per;
    int end = min(E, beg + per);
    int nv = (end - beg) >> 2;
    const iv4* d4 = (const iv4*)(dst + beg);
    const iv4* s4 = (const iv4*)(src + beg);
    for (int i = t; i < nv; i += 256) {
        iv4 dv = __builtin_nontemporal_load(d4 + i);
        iv4 sv = __builtin_nontemporal_load(s4 + i);
        int x;
        x = dv.x - base; if ((unsigned)x < CHUNK) col[atomicAdd(&cur[x], 1)] = sv.x;
        x = dv.y - base; if ((unsigned)x < CHUNK) col[atomicAdd(&cur[x], 1)] = sv.y;
        x = dv.z - base; if ((unsigned)x < CHUNK) col[atomicAdd(&cur[x], 1)] = sv.z;
        x = dv.w - base; if ((unsigned)x < CHUNK) col[atomicAdd(&cur[x], 1)] = sv.w;
    }
    for (int e = beg + (nv << 2) + t; e < end; e += 256) {
        int x = dst[e] - base;
        if ((unsigned)x < CHUNK) col[atomicAdd(&cur[x], 1)] = src[e];
    }
}

// ---------------- dense layers ----------------

// Fused weight prep: blocks 0..7 -> wt1[c][k]=bf16(W1[k][c]); blocks 8..10 ->
// wt2[c][k]=bf16(W2[k][c]) for c<40, zeros 40<=c<48.
__global__ __launch_bounds__(256) void wprep_kernel(const float* __restrict__ W1, unsigned short* __restrict__ wt1,
                                                    const float* __restrict__ W2, unsigned short* __restrict__ wt2) {
    int bid = blockIdx.x;
    if (bid < 8) {
        int tid = bid * 256 + threadIdx.x;          // 0..2047
        int c = tid & 127, kg = tid >> 7;
        unsigned p[4];
        #pragma unroll
        for (int j = 0; j < 4; ++j) {
            float v0 = W1[(kg * 8 + 2 * j) * 128 + c];
            float v1 = W1[(kg * 8 + 2 * j + 1) * 128 + c];
            p[j] = pack_bf2(v0, v1);
        }
        *(uint4*)(wt1 + (size_t)c * 128 + kg * 8) = make_uint4(p[0], p[1], p[2], p[3]);
    } else {
        int tid = (bid - 8) * 256 + threadIdx.x;    // 0..767
        int c = tid >> 4, kg = tid & 15;            // c 0..47
        unsigned p[4];
        #pragma unroll
        for (int j = 0; j < 4; ++j) {
            float v0 = (c < 40) ? W2[(kg * 8 + 2 * j) * 40 + c] : 0.f;
            float v1 = (c < 40) ? W2[(kg * 8 + 2 * j + 1) * 40 + c] : 0.f;
            p[j] = pack_bf2(v0, v1);
        }
        *(uint4*)(wt2 + (size_t)c * 128 + kg * 8) = make_uint4(p[0], p[1], p[2], p[3]);
    }
}

// h1[n][j] = bf16( (ns*x)bf16 @ W1 ) via mfma_f32_16x16x32_bf16, flat [n][128].
__global__ __launch_bounds__(256) void gemm1_kernel(const float* __restrict__ x, const float* __restrict__ norm,
                                                    const unsigned short* __restrict__ wt,
                                                    unsigned short* __restrict__ h1u, int N) {
    __shared__ uint4 xs4[1024];                 // 64 rows x 256B (bf16, XOR-swizzled)
    char* xsb = (char*)xs4;
    int t = threadIdx.x;
    int rb = blockIdx.x * 64;
    #pragma unroll
    for (int i = 0; i < 8; ++i) {
        int idx = i * 256 + t;
        int row = idx >> 5, k4 = (idx & 31) << 2;
        int gr = rb + row;
        float4 v = make_float4(0.f, 0.f, 0.f, 0.f);
        if (gr < N) {
            v = *(const float4*)(x + (size_t)gr * 128 + k4);
            float nm = norm[gr];
            v.x *= nm; v.y *= nm; v.z *= nm; v.w *= nm;
        }
        int boff = row * 256 + ((k4 * 2) ^ ((row & 7) << 4));
        *(uint2*)(xsb + boff) = make_uint2(pack_bf2(v.x, v.y), pack_bf2(v.z, v.w));
    }
    __syncthreads();
    int w = t >> 6, lane = t & 63;
    int lrow = lane & 15, g = lane >> 4;
    int sw = (lrow & 7) << 4;
    int rloc = (w << 4) + lrow;
    short8 a[4];
    #pragma unroll
    for (int kt = 0; kt < 4; ++kt)
        a[kt] = *(const short8*)(xsb + rloc * 256 + ((kt * 64 + g * 16) ^ sw));
    f32x4 acc[8];
    #pragma unroll
    for (int ct = 0; ct < 8; ++ct) acc[ct] = (f32x4){0.f, 0.f, 0.f, 0.f};
    #pragma unroll
    for (int ct = 0; ct < 8; ++ct) {
        const unsigned short* wb = wt + (size_t)(ct * 16 + lrow) * 128 + g * 8;
        short8 b0 = *(const short8*)(wb);
        short8 b1 = *(const short8*)(wb + 32);
        short8 b2 = *(const short8*)(wb + 64);
        short8 b3 = *(const short8*)(wb + 96);
        acc[ct] = __builtin_amdgcn_mfma_f32_16x16x32_bf16(a[0], b0, acc[ct], 0, 0, 0);
        acc[ct] = __builtin_amdgcn_mfma_f32_16x16x32_bf16(a[1], b1, acc[ct], 0, 0, 0);
        acc[ct] = __builtin_amdgcn_mfma_f32_16x16x32_bf16(a[2], b2, acc[ct], 0, 0, 0);
        acc[ct] = __builtin_amdgcn_mfma_f32_16x16x32_bf16(a[3], b3, acc[ct], 0, 0, 0);
    }
    int rbase = rb + (w << 4) + g * 4;
    #pragma unroll
    for (int reg = 0; reg < 4; ++reg) {
        int rowg = rbase + reg;
        if (rowg < N) {
            #pragma unroll
            for (int ct = 0; ct < 8; ++ct)
                h1u[(size_t)rowg * 128 + ct * 16 + lrow] = (unsigned short)f2bf_bits(acc[ct][reg]);
        }
    }
}

// w[n][0..40) = y[n] @ W2, rows 40 bf16 (80B). y bf16 [n][128].
__global__ __launch_bounds__(256) void gemmW2_kernel(const unsigned short* __restrict__ yu,
                                                     const unsigned short* __restrict__ wt2,
                                                     unsigned short* __restrict__ wu, int N) {
    __shared__ uint4 xs4[1024];
    char* xsb = (char*)xs4;
    int t = threadIdx.x;
    int rb = blockIdx.x * 64;
    #pragma unroll
    for (int i = 0; i < 8; ++i) {
        int idx = i * 256 + t;
        int row = idx >> 5, q = idx & 31;
        int gr = rb + row;
        uint2 v = make_uint2(0u, 0u);
        if (gr < N) v = *(const uint2*)(yu + (size_t)gr * 128 + q * 4);
        int boff = row * 256 + ((q * 8) ^ ((row & 7) << 4));
        *(uint2*)(xsb + boff) = v;
    }
    __syncthreads();
    int w = t >> 6, lane = t & 63;
    int lrow = lane & 15, g = lane >> 4;
    int sw = (lrow & 7) << 4;
    int rloc = (w << 4) + lrow;
    short8 a[4];
    #pragma unroll
    for (int kt = 0; kt < 4; ++kt)
        a[kt] = *(const short8*)(xsb + rloc * 256 + ((kt * 64 + g * 16) ^ sw));
    f32x4 acc[3];
    #pragma unroll
    for (int ct = 0; ct < 3; ++ct) acc[ct] = (f32x4){0.f, 0.f, 0.f, 0.f};
    #pragma unroll
    for (int ct = 0; ct < 3; ++ct) {
        const unsigned short* wb = wt2 + (size_t)(ct * 16 + lrow) * 128 + g * 8;
        short8 b0 = *(const short8*)(wb);
        short8 b1 = *(const short8*)(wb + 32);
        short8 b2 = *(const short8*)(wb + 64);
        short8 b3 = *(const short8*)(wb + 96);
        acc[ct] = __builtin_amdgcn_mfma_f32_16x16x32_bf16(a[0], b0, acc[ct], 0, 0, 0);
        acc[ct] = __builtin_amdgcn_mfma_f32_16x16x32_bf16(a[1], b1, acc[ct], 0, 0, 0);
        acc[ct] = __builtin_amdgcn_mfma_f32_16x16x32_bf16(a[2], b2, acc[ct], 0, 0, 0);
        acc[ct] = __builtin_amdgcn_mfma_f32_16x16x32_bf16(a[3], b3, acc[ct], 0, 0, 0);
    }
    int rbase = rb + (w << 4) + g * 4;
    #pragma unroll
    for (int reg = 0; reg < 4; ++reg) {
        int rowg = rbase + reg;
        if (rowg < N) {
            #pragma unroll
            for (int ct = 0; ct < 3; ++ct) {
                int c = ct * 16 + lrow;
                if (c < 40) wu[(size_t)rowg * 40 + c] = (unsigned short)f2bf_bits(acc[ct][reg]);
            }
        }
    }
}

// ---------------- gathers (one node per wave) ----------------

#define ACC8(v)  { a0 += bflo(v.x); a1 += bfhi(v.x); a2 += bflo(v.y); a3 += bfhi(v.y); \
                   a4 += bflo(v.z); a5 += bfhi(v.z); a6 += bflo(v.w); a7 += bfhi(v.w); }

// y[n] = ns * relu( (sum h1[src]) * nd + b1 ), flat [n][128] bf16.
__global__ __launch_bounds__(256) void agg1_kernel(const int* __restrict__ row_ptr, const int* __restrict__ col,
                                                   const uint4* __restrict__ h1q, const float* __restrict__ norm_dst,
                                                   const float* __restrict__ norm_src,
                                                   const float* __restrict__ b1, uint4* __restrict__ yq, int N) {
    int t = threadIdx.x;
    int wid = t >> 6, lane = t & 63;
    int g = lane >> 4, f = lane & 15;
    int n = blockIdx.x * 4 + wid;
    if (n >= N) return;
    int beg = row_ptr[n], deg = row_ptr[n + 1] - beg;
    const int* cp = col + beg;
    float a0 = 0, a1 = 0, a2 = 0, a3 = 0, a4 = 0, a5 = 0, a6 = 0, a7 = 0;
    int e = 0;
    for (; e + 16 <= deg; e += 16) {
        int s0 = cp[e + g];
        int s1 = cp[e + 4 + g];
        int s2 = cp[e + 8 + g];
        int s3 = cp[e + 12 + g];
        uint4 v0 = h1q[(size_t)s0 * 16 + f];
        uint4 v1 = h1q[(size_t)s1 * 16 + f];
        uint4 v2 = h1q[(size_t)s2 * 16 + f];
        uint4 v3 = h1q[(size_t)s3 * 16 + f];
        ACC8(v0); ACC8(v1); ACC8(v2); ACC8(v3);
    }
    for (; e < deg; e += 4) {
        int idx = e + g;
        if (idx < deg) {
            uint4 v = h1q[(size_t)cp[idx] * 16 + f];
            ACC8(v);
        }
    }
    a0 += __shfl_xor(a0, 16, 64); a0 += __shfl_xor(a0, 32, 64);
    a1 += __shfl_xor(a1, 16, 64); a1 += __shfl_xor(a1, 32, 64);
    a2 += __shfl_xor(a2, 16, 64); a2 += __shfl_xor(a2, 32, 64);
    a3 += __shfl_xor(a3, 16, 64); a3 += __shfl_xor(a3, 32, 64);
    a4 += __shfl_xor(a4, 16, 64); a4 += __shfl_xor(a4, 32, 64);
    a5 += __shfl_xor(a5, 16, 64); a5 += __shfl_xor(a5, 32, 64);
    a6 += __shfl_xor(a6, 16, 64); a6 += __shfl_xor(a6, 32, 64);
    a7 += __shfl_xor(a7, 16, 64); a7 += __shfl_xor(a7, 32, 64);
    if (g == 0) {
        float nd = norm_dst[n];
        float ns = norm_src[n];
        float4 bA = *(const float4*)(b1 + f * 8);
        float4 bB = *(const float4*)(b1 + f * 8 + 4);
        float o0 = ns * fmaxf(a0 * nd + bA.x, 0.f);
        float o1 = ns * fmaxf(a1 * nd + bA.y, 0.f);
        float o2 = ns * fmaxf(a2 * nd + bA.z, 0.f);
        float o3 = ns * fmaxf(a3 * nd + bA.w, 0.f);
        float o4 = ns * fmaxf(a4 * nd + bB.x, 0.f);
        float o5 = ns * fmaxf(a5 * nd + bB.y, 0.f);
        float o6 = ns * fmaxf(a6 * nd + bB.z, 0.f);
        float o7 = ns * fmaxf(a7 * nd + bB.w, 0.f);
        uint4 p;
        p.x = pack_bf2(o0, o1); p.y = pack_bf2(o2, o3);
        p.z = pack_bf2(o4, o5); p.w = pack_bf2(o6, o7);
        yq[(size_t)n * 16 + f] = p;
    }
}

// out[n][j] = (sum w[src][j]) * nd + b2[j], j<40. w rows 80B = 5 uint4,
// lanes f<5 active (no padding fetched); g=lane>>3 covers 8 edges.
__global__ __launch_bounds__(256) void aggZ_kernel(const int* __restrict__ row_ptr, const int* __restrict__ col,
                                                   const uint4* __restrict__ wq, const float* __restrict__ norm_dst,
                                                   const float* __restrict__ b2, float* __restrict__ out, int N) {
    int t = threadIdx.x;
    int wid = t >> 6, lane = t & 63;
    int g = lane >> 3, f = lane & 7;
    bool act = f < 5;
    int n = blockIdx.x * 4 + wid;
    if (n >= N) return;
    int beg = row_ptr[n], deg = row_ptr[n + 1] - beg;
    const int* cp = col + beg;
    float a0 = 0, a1 = 0, a2 = 0, a3 = 0, a4 = 0, a5 = 0, a6 = 0, a7 = 0;
    int e = 0;
    for (; e + 32 <= deg; e += 32) {
        int s0 = cp[e + g];
        int s1 = cp[e + 8 + g];
        int s2 = cp[e + 16 + g];
        int s3 = cp[e + 24 + g];
        if (act) {
            uint4 v0 = wq[(size_t)s0 * 5 + f];
            uint4 v1 = wq[(size_t)s1 * 5 + f];
            uint4 v2 = wq[(size_t)s2 * 5 + f];
            uint4 v3 = wq[(size_t)s3 * 5 + f];
            ACC8(v0); ACC8(v1); ACC8(v2); ACC8(v3);
        }
    }
    for (; e < deg; e += 8) {
        int idx = e + g;
        if (idx < deg && act) {
            uint4 v = wq[(size_t)cp[idx] * 5 + f];
            ACC8(v);
        }
    }
    a0 += __shfl_xor(a0, 8, 64); a0 += __shfl_xor(a0, 16, 64); a0 += __shfl_xor(a0, 32, 64);
    a1 += __shfl_xor(a1, 8, 64); a1 += __shfl_xor(a1, 16, 64); a1 += __shfl_xor(a1, 32, 64);
    a2 += __shfl_xor(a2, 8, 64); a2 += __shfl_xor(a2, 16, 64); a2 += __shfl_xor(a2, 32, 64);
    a3 += __shfl_xor(a3, 8, 64); a3 += __shfl_xor(a3, 16, 64); a3 += __shfl_xor(a3, 32, 64);
    a4 += __shfl_xor(a4, 8, 64); a4 += __shfl_xor(a4, 16, 64); a4 += __shfl_xor(a4, 32, 64);
    a5 += __shfl_xor(a5, 8, 64); a5 += __shfl_xor(a5, 16, 64); a5 += __shfl_xor(a5, 32, 64);
    a6 += __shfl_xor(a6, 8, 64); a6 += __shfl_xor(a6, 16, 64); a6 += __shfl_xor(a6, 32, 64);
    a7 += __shfl_xor(a7, 8, 64); a7 += __shfl_xor(a7, 16, 64); a7 += __shfl_xor(a7, 32, 64);
    if (g == 0 && act) {
        float nd = norm_dst[n];
        int j0 = f * 8;
        float4 bA = *(const float4*)(b2 + j0);
        float4 bB = *(const float4*)(b2 + j0 + 4);
        float* op = out + (size_t)n * 40 + j0;
        *(float4*)(op)     = make_float4(a0 * nd + bA.x, a1 * nd + bA.y, a2 * nd + bA.z, a3 * nd + bA.w);
        *(float4*)(op + 4) = make_float4(a4 * nd + bB.x, a5 * nd + bB.y, a6 * nd + bB.z, a7 * nd + bB.w);
    }
}

extern "C" void kernel_launch(void* const* d_in, const int* in_sizes, int n_in,
                              void* d_out, int out_size, void* d_ws, size_t ws_size,
                              hipStream_t stream) {
    const float* x  = (const float*)d_in[0];
    const int* src  = (const int*)d_in[1];
    const int* dst  = (const int*)d_in[2];
    const float* W1 = (const float*)d_in[3];
    const float* b1 = (const float*)d_in[4];
    const float* W2 = (const float*)d_in[5];
    const float* b2 = (const float*)d_in[6];
    float* out = (float*)d_out;

    int N = in_sizes[0] / 128;
    int E = in_sizes[1];
    int NPAD = (N + 63) & ~63;
    int NCHUNKS = (N + CHUNK - 1) >> CHUNK_SHIFT;
    int per = ((E + NSLICES - 1) / NSLICES + 3) & ~3;
    int NB = (N + 255) / 256;   // <= 256

    float* ws = (float*)d_ws;
    float* norm_src = ws;                                       // NPAD floats
    float* norm_dst = ws + NPAD;                                // NPAD floats
    int* deg_dst_i  = (int*)(ws + 2 * (size_t)NPAD);            // NPAD ints
    int* row_ptr    = (int*)(ws + 3 * (size_t)NPAD);            // N+1 ints
    int* bsum       = (int*)(ws + 4 * (size_t)NPAD);            // 256 ints
    unsigned short* wt1 = (unsigned short*)(ws + 4 * (size_t)NPAD + 256);        // 16384 bf16
    unsigned short* wt2 = (unsigned short*)(ws + 4 * (size_t)NPAD + 256 + 8192); // 6144 bf16
    int* col        = (int*)(ws + 4 * (size_t)NPAD + 256 + 8192 + 3072);         // E ints
    size_t h1_off   = ((size_t)4 * NPAD + 256 + 8192 + 3072 + E + 15) & ~(size_t)15;
    unsigned short* h1u = (unsigned short*)(ws + h1_off);       // NPAD*128 bf16 (12.8MB)
    uint4* h1q      = (uint4*)h1u;
    unsigned short* yu = h1u + (size_t)NPAD * 128;              // NPAD*128 bf16 (slot 2)
    uint4* yq       = (uint4*)yu;
    unsigned short* wu = h1u;                                   // w reuses h1 slot (NPAD*40 bf16)
    uint4* wq       = (uint4*)wu;
    unsigned int* part = (unsigned int*)h1u;                    // 16.8MB, dead before gemm1

    dim3 cgrid(NSLICES, NCHUNKS);
    wprep_kernel<<<11, 256, 0, stream>>>(W1, wt1, W2, wt2);
    count_kernel<<<cgrid, 256, 0, stream>>>(src, dst, part, E, per);
    reduce_kernel<<<NB, 256, 0, stream>>>(part, norm_src, norm_dst, deg_dst_i, bsum, N);
    scanB_kernel<<<1, 256, 0, stream>>>(bsum, NB, row_ptr, N);
    offsets_kernel<<<NB, 256, 0, stream>>>(part, deg_dst_i, bsum, row_ptr, N);
    scatter_kernel<<<cgrid, 256, 0, stream>>>(src, dst, part, col, E, per);
    gemm1_kernel<<<(N + 63) / 64, 256, 0, stream>>>(x, norm_src, wt1, h1u, N);
    agg1_kernel<<<(N + 3) / 4, 256, 0, stream>>>(row_ptr, col, h1q, norm_dst, norm_src, b1, yq, N);
    gemmW2_kernel<<<(N + 63) / 64, 256, 0, stream>>>(yu, wt2, wu, N);
    aggZ_kernel<<<(N + 3) / 4, 256, 0, stream>>>(row_ptr, col, wq, norm_dst, b2, out, N);
}